// Round 8
// baseline (781.351 us; speedup 1.0000x reference)
//
#include <hip/hip_runtime.h>
#include <hip/hip_bf16.h>
#include <math.h>

#define BATCH 8
#define NPTS  2048
#define KNN   20
#define NEG_INF (-3.402823466e38f)

static __device__ __forceinline__ float bn_scale(float g){ return g * rsqrtf(1.0f + 1e-5f); }

// bf16 round-to-nearest-even
static __device__ __forceinline__ unsigned short bf16r(float f){
  unsigned int u = __float_as_uint(f);
  unsigned int r = (u + 0x7fffu + ((u >> 16) & 1u)) >> 16;
  return (unsigned short)r;
}
static __device__ __forceinline__ float bf2f(unsigned short h){
  return __uint_as_float((unsigned int)h << 16);
}
// ordered-int encode/decode for float max via atomicMax(uint)
static __device__ __forceinline__ unsigned int fenc(float f){
  unsigned int u = __float_as_uint(f);
  return (u & 0x80000000u) ? ~u : (u | 0x80000000u);
}
static __device__ __forceinline__ float fdec(unsigned int e){
  return __uint_as_float((e & 0x80000000u) ? (e & 0x7fffffffu) : ~e);
}

using bfrag = __attribute__((ext_vector_type(8))) short;  // 8 bf16 (4 VGPRs)
using f32x4 = __attribute__((ext_vector_type(4))) float;  // 4 fp32 acc
using f32x2 = __attribute__((ext_vector_type(2))) float;  // packed pair -> v_pk_fma_f32

// ---- wave argmax: value-only DPP max scan (6 fused steps), then index resolve ----
static __device__ __forceinline__ int wave_argmax_idx(float bv, int bi){
  float v = bv;
  #define AMAX_STEP(CTRL) { \
    int _t = __builtin_amdgcn_update_dpp(__float_as_int(NEG_INF), __float_as_int(v), \
                                         CTRL, 0xf, 0xf, false); \
    v = fmaxf(v, __int_as_float(_t)); }
  AMAX_STEP(0x111)  // row_shr:1
  AMAX_STEP(0x112)  // row_shr:2
  AMAX_STEP(0x114)  // row_shr:4
  AMAX_STEP(0x118)  // row_shr:8
  AMAX_STEP(0x142)  // row_bcast:15
  AMAX_STEP(0x143)  // row_bcast:31
  #undef AMAX_STEP
  const float vmax = __int_as_float(__builtin_amdgcn_readlane(__float_as_int(v), 63));
  unsigned long long m = __ballot(bv == vmax);           // >=1 lane set
  int widx = __builtin_amdgcn_readlane(bi, (int)__builtin_ctzll(m));
  if (m & (m - 1)){                                      // rare: cross-lane value tie
    unsigned long long r = m & (m - 1);
    while (r){
      int c = __builtin_amdgcn_readlane(bi, (int)__builtin_ctzll(r));
      widx = min(widx, c);
      r &= r - 1;
    }
  }
  return widx;
}
// ---- DPP wave sum (identity 0.0 injected); total broadcast from lane 63 ----
template<int CTRL>
static __device__ __forceinline__ float dpp_fadd(float v){
  int ov = __builtin_amdgcn_update_dpp(0, __float_as_int(v), CTRL, 0xf, 0xf, false);
  return v + __int_as_float(ov);
}
static __device__ __forceinline__ float wave_sum(float v){
  v = dpp_fadd<0x111>(v); v = dpp_fadd<0x112>(v);
  v = dpp_fadd<0x114>(v); v = dpp_fadd<0x118>(v);
  v = dpp_fadd<0x142>(v); v = dpp_fadd<0x143>(v);
  return __int_as_float(__builtin_amdgcn_readlane(__float_as_int(v), 63));
}

// ---------------- kNN v17: 2-phase pipeline (C>=8) -----------------------------------
// Phase A: distance for points n0..n0+3 -> write/scan. Phase B: selection of rep0 with
// rep1's FMA stream interleaved into the sel rounds (fills the DPP chains' latency
// shadows; re-loads are L2-hot). Per-point FMA order unchanged -> bit-exact.
template<int C, int M>
__global__ __launch_bounds__(256, 4) void knn_kernel(const float* __restrict__ X,
                                                     const float* __restrict__ sq,
                                                     int* __restrict__ idxout){
  const int b = blockIdx.y;
  const int n0 = blockIdx.x * M;
  const int t = threadIdx.x;
  __shared__ __align__(16) float dist[4][NPTS];   // the ONLY LDS: 32 KB
  const float* xb = X + (size_t)b*C*NPTS;
  const int m0 = t * 8;
  const int wv = t >> 6, lane = t & 63;
  const int su0 = (((2*t)   ) ^ ((t>>2)&7)) * 4;
  const int su1 = (((2*t)+1 ) ^ ((t>>2)&7)) * 4;

  if constexpr (C >= 8){
    // ---------- phase A: distance for centers n0..n0+3 ----------
    f32x2 a0[4][4];
    #pragma unroll
    for (int r=0;r<4;++r)
      #pragma unroll
      for (int j=0;j<4;++j) a0[r][j] = (f32x2){0.f,0.f};
    #pragma unroll 2
    for (int c=0;c<C;++c){
      const float4 xa = *(const float4*)&xb[(size_t)c*NPTS + m0];
      const float4 xc = *(const float4*)&xb[(size_t)c*NPTS + m0 + 4];
      const f32x2 xm2[4] = {(f32x2){xa.x,xa.y},(f32x2){xa.z,xa.w},
                            (f32x2){xc.x,xc.y},(f32x2){xc.z,xc.w}};
      const float4 cq = *(const float4*)&xb[(size_t)c*NPTS + n0];   // uniform 16B
      const float cvr[4] = {cq.x,cq.y,cq.z,cq.w};
      #pragma unroll
      for (int r=0;r<4;++r){
        const f32x2 cv2 = (f32x2){cvr[r],cvr[r]};
        #pragma unroll
        for (int j=0;j<4;++j) a0[r][j] += cv2*xm2[j];   // v_pk_fma_f32
      }
    }
    {
      const float4 sa = *(const float4*)&sq[b*NPTS + m0];
      const float4 sb = *(const float4*)&sq[b*NPTS + m0 + 4];
      const f32x2 sm2[4] = {(f32x2){sa.x,sa.y},(f32x2){sa.z,sa.w},
                            (f32x2){sb.x,sb.y},(f32x2){sb.z,sb.w}};
      const float4 sqc = *(const float4*)&sq[b*NPTS + n0];          // uniform
      const float sir[4] = {sqc.x,sqc.y,sqc.z,sqc.w};
      #pragma unroll
      for (int r=0;r<4;++r){
        const f32x2 si2 = (f32x2){sir[r],sir[r]};
        #pragma unroll
        for (int j=0;j<4;++j) a0[r][j] = (f32x2){2.f,2.f}*a0[r][j] - si2 - sm2[j];
      }
    }
    #pragma unroll
    for (int i=0;i<4;++i){
      *(float4*)&dist[i][su0] = make_float4(a0[i][0].x,a0[i][0].y,a0[i][1].x,a0[i][1].y);
      *(float4*)&dist[i][su1] = make_float4(a0[i][2].x,a0[i][2].y,a0[i][3].x,a0[i][3].y);
    }
    __syncthreads();
    // scan rep0: per-lane sorted top-4 (value desc, idx asc)
    float s0=NEG_INF,s1=NEG_INF,s2=NEG_INF,s3=NEG_INF;
    int   i0=0x7fffffff,i1=0x7fffffff,i2=0x7fffffff,i3=0x7fffffff;
    #pragma unroll
    for (int jb=0;jb<8;++jb){
      const int u = lane*8 + jb;
      const float4 q = *(const float4*)&dist[wv][(u ^ (lane&7))*4];
      const float qe[4] = {q.x, q.y, q.z, q.w};
      #pragma unroll
      for (int e=0;e<4;++e){
        const float v = qe[e];
        const int   m = lane*32 + jb*4 + e;
        const bool b0 = v > s0, b1 = v > s1, b2 = v > s2, b3 = v > s3;
        const float n0_ = b0 ? v : s0;            const int q0 = b0 ? m : i0;
        const float n1_ = b0 ? s0 : (b1 ? v : s1); const int q1 = b0 ? i0 : (b1 ? m : i1);
        const float n2_ = b1 ? s1 : (b2 ? v : s2); const int q2 = b1 ? i1 : (b2 ? m : i2);
        const float n3_ = b2 ? s2 : (b3 ? v : s3); const int q3 = b2 ? i2 : (b3 ? m : i3);
        s0=n0_;s1=n1_;s2=n2_;s3=n3_; i0=q0;i1=q1;i2=q2;i3=q3;
      }
    }
    // ---------- phase B: selection rep0 + rep1 FMA interleave ----------
    constexpr int CHUNK = C/16;     // 16 carrying rounds cover all C
    f32x2 a1[4][4];
    #pragma unroll
    for (int r=0;r<4;++r)
      #pragma unroll
      for (int j=0;j<4;++j) a1[r][j] = (f32x2){0.f,0.f};
    {
      int rem = 4;
      int* row = idxout + ((size_t)b*NPTS + n0 + wv)*KNN;
      #pragma unroll 1
      for (int sel=0; sel<KNN; ++sel){
        const int widx = wave_argmax_idx(s0, i0);
        if (lane == 0) row[sel] = widx;
        if ((widx >> 5) == lane){
          const float lastv = s0; const int lasti = i0;
          s0=s1;i0=i1; s1=s2;i1=i2; s2=s3;i2=i3;
          rem--;
          if (rem == 0){
            float nv = NEG_INF; int ni = 0x7fffffff;
            #pragma unroll 2
            for (int jb=0;jb<8;++jb){
              const int u = lane*8 + jb;
              const float4 q = *(const float4*)&dist[wv][(u ^ (lane&7))*4];
              const float qe[4] = {q.x, q.y, q.z, q.w};
              #pragma unroll
              for (int e=0;e<4;++e){
                const float vv = qe[e];
                const int   mi = lane*32 + jb*4 + e;
                const bool ok = (vv < lastv) || (vv == lastv && mi > lasti);
                if (ok && vv > nv){ nv = vv; ni = mi; }
              }
            }
            s0 = nv; i0 = ni; rem = 1;
          }
        }
        if (sel < 16){                 // rep1 distance stream fills DPP latency shadows
          const float* cb = xb + (size_t)(sel*CHUNK)*NPTS;
          #pragma unroll
          for (int u=0;u<CHUNK;++u){
            const float4 xa = *(const float4*)&cb[(size_t)u*NPTS + m0];
            const float4 xc = *(const float4*)&cb[(size_t)u*NPTS + m0 + 4];
            const f32x2 xm2[4] = {(f32x2){xa.x,xa.y},(f32x2){xa.z,xa.w},
                                  (f32x2){xc.x,xc.y},(f32x2){xc.z,xc.w}};
            const float4 cq = *(const float4*)&cb[(size_t)u*NPTS + n0 + 4];  // uniform
            const float cvr[4] = {cq.x,cq.y,cq.z,cq.w};
            #pragma unroll
            for (int r=0;r<4;++r){
              const f32x2 cv2 = (f32x2){cvr[r],cvr[r]};
              #pragma unroll
              for (int j=0;j<4;++j) a1[r][j] += cv2*xm2[j];
            }
          }
        }
      }
    }
    // rep1 epilogue
    {
      const float4 sa = *(const float4*)&sq[b*NPTS + m0];
      const float4 sb = *(const float4*)&sq[b*NPTS + m0 + 4];
      const f32x2 sm2[4] = {(f32x2){sa.x,sa.y},(f32x2){sa.z,sa.w},
                            (f32x2){sb.x,sb.y},(f32x2){sb.z,sb.w}};
      const float4 sqc = *(const float4*)&sq[b*NPTS + n0 + 4];      // uniform
      const float sir[4] = {sqc.x,sqc.y,sqc.z,sqc.w};
      #pragma unroll
      for (int r=0;r<4;++r){
        const f32x2 si2 = (f32x2){sir[r],sir[r]};
        #pragma unroll
        for (int j=0;j<4;++j) a1[r][j] = (f32x2){2.f,2.f}*a1[r][j] - si2 - sm2[j];
      }
    }
    __syncthreads();                   // all waves done reading rep0 dist
    #pragma unroll
    for (int i=0;i<4;++i){
      *(float4*)&dist[i][su0] = make_float4(a1[i][0].x,a1[i][0].y,a1[i][1].x,a1[i][1].y);
      *(float4*)&dist[i][su1] = make_float4(a1[i][2].x,a1[i][2].y,a1[i][3].x,a1[i][3].y);
    }
    __syncthreads();
    // scan rep1
    float t0=NEG_INF,t1=NEG_INF,t2=NEG_INF,t3=NEG_INF;
    int   k0=0x7fffffff,k1=0x7fffffff,k2=0x7fffffff,k3=0x7fffffff;
    #pragma unroll
    for (int jb=0;jb<8;++jb){
      const int u = lane*8 + jb;
      const float4 q = *(const float4*)&dist[wv][(u ^ (lane&7))*4];
      const float qe[4] = {q.x, q.y, q.z, q.w};
      #pragma unroll
      for (int e=0;e<4;++e){
        const float v = qe[e];
        const int   m = lane*32 + jb*4 + e;
        const bool b0 = v > t0, b1 = v > t1, b2 = v > t2, b3 = v > t3;
        const float n0_ = b0 ? v : t0;            const int q0 = b0 ? m : k0;
        const float n1_ = b0 ? t0 : (b1 ? v : t1); const int q1 = b0 ? k0 : (b1 ? m : k1);
        const float n2_ = b1 ? t1 : (b2 ? v : t2); const int q2 = b1 ? k1 : (b2 ? m : k2);
        const float n3_ = b2 ? t2 : (b3 ? v : t3); const int q3 = b2 ? k2 : (b3 ? m : k3);
        t0=n0_;t1=n1_;t2=n2_;t3=n3_; k0=q0;k1=q1;k2=q2;k3=q3;
      }
    }
    {
      int rem = 4;
      int* row = idxout + ((size_t)b*NPTS + n0 + 4 + wv)*KNN;
      #pragma unroll 1
      for (int sel=0; sel<KNN; ++sel){
        const int widx = wave_argmax_idx(t0, k0);
        if (lane == 0) row[sel] = widx;
        if ((widx >> 5) == lane){
          const float lastv = t0; const int lasti = k0;
          t0=t1;k0=k1; t1=t2;k1=k2; t2=t3;k2=k3;
          rem--;
          if (rem == 0){
            float nv = NEG_INF; int ni = 0x7fffffff;
            #pragma unroll 2
            for (int jb=0;jb<8;++jb){
              const int u = lane*8 + jb;
              const float4 q = *(const float4*)&dist[wv][(u ^ (lane&7))*4];
              const float qe[4] = {q.x, q.y, q.z, q.w};
              #pragma unroll
              for (int e=0;e<4;++e){
                const float vv = qe[e];
                const int   mi = lane*32 + jb*4 + e;
                const bool ok = (vv < lastv) || (vv == lastv && mi > lasti);
                if (ok && vv > nv){ nv = vv; ni = mi; }
              }
            }
            t0 = nv; k0 = ni; rem = 1;
          }
        }
      }
    }
  } else {
    // ---------- C==3: original combined path ----------
    f32x2 acc2[M][4];
    #pragma unroll
    for (int i=0;i<M;++i)
      #pragma unroll
      for (int j=0;j<4;++j) acc2[i][j] = (f32x2){0.f, 0.f};
    #pragma unroll
    for (int c=0;c<C;++c){
      const float4 xa = *(const float4*)&xb[(size_t)c*NPTS + m0];
      const float4 xc = *(const float4*)&xb[(size_t)c*NPTS + m0 + 4];
      const f32x2 xm2[4] = {(f32x2){xa.x,xa.y}, (f32x2){xa.z,xa.w},
                            (f32x2){xc.x,xc.y}, (f32x2){xc.z,xc.w}};
      #pragma unroll
      for (int i4=0; i4<M/4; ++i4){
        const float4 cq = *(const float4*)&xb[(size_t)c*NPTS + n0 + i4*4];
        const float cvr[4] = {cq.x, cq.y, cq.z, cq.w};
        #pragma unroll
        for (int r=0;r<4;++r){
          const f32x2 cv2 = (f32x2){cvr[r], cvr[r]};
          #pragma unroll
          for (int j=0;j<4;++j) acc2[i4*4+r][j] += cv2*xm2[j];
        }
      }
    }
    {
      const float4 sa = *(const float4*)&sq[b*NPTS + m0];
      const float4 sb = *(const float4*)&sq[b*NPTS + m0 + 4];
      const f32x2 sm2[4] = {(f32x2){sa.x,sa.y}, (f32x2){sa.z,sa.w},
                            (f32x2){sb.x,sb.y}, (f32x2){sb.z,sb.w}};
      #pragma unroll
      for (int i4=0; i4<M/4; ++i4){
        const float4 sqc = *(const float4*)&sq[b*NPTS + n0 + i4*4];
        const float sir[4] = {sqc.x, sqc.y, sqc.z, sqc.w};
        #pragma unroll
        for (int r=0;r<4;++r){
          const f32x2 si2 = (f32x2){sir[r], sir[r]};
          #pragma unroll
          for (int j=0;j<4;++j)
            acc2[i4*4+r][j] = (f32x2){2.f,2.f}*acc2[i4*4+r][j] - si2 - sm2[j];
        }
      }
    }
    #pragma unroll
    for (int rep=0; rep<M/4; ++rep){
      #pragma unroll
      for (int i=0;i<4;++i){
        const int r = rep*4 + i;
        *(float4*)&dist[i][su0] = make_float4(acc2[r][0].x, acc2[r][0].y, acc2[r][1].x, acc2[r][1].y);
        *(float4*)&dist[i][su1] = make_float4(acc2[r][2].x, acc2[r][2].y, acc2[r][3].x, acc2[r][3].y);
      }
      __syncthreads();
      float s0=NEG_INF,s1=NEG_INF,s2=NEG_INF,s3=NEG_INF;
      int   i0=0x7fffffff,i1=0x7fffffff,i2=0x7fffffff,i3=0x7fffffff;
      #pragma unroll
      for (int jb=0;jb<8;++jb){
        const int u = lane*8 + jb;
        const float4 q = *(const float4*)&dist[wv][(u ^ (lane&7))*4];
        const float qe[4] = {q.x, q.y, q.z, q.w};
        #pragma unroll
        for (int e=0;e<4;++e){
          const float v = qe[e];
          const int   m = lane*32 + jb*4 + e;
          const bool b0 = v > s0, b1 = v > s1, b2 = v > s2, b3 = v > s3;
          const float n0_ = b0 ? v : s0;            const int q0 = b0 ? m : i0;
          const float n1_ = b0 ? s0 : (b1 ? v : s1); const int q1 = b0 ? i0 : (b1 ? m : i1);
          const float n2_ = b1 ? s1 : (b2 ? v : s2); const int q2 = b1 ? i1 : (b2 ? m : i2);
          const float n3_ = b2 ? s2 : (b3 ? v : s3); const int q3 = b2 ? i2 : (b3 ? m : i3);
          s0=n0_;s1=n1_;s2=n2_;s3=n3_; i0=q0;i1=q1;i2=q2;i3=q3;
        }
      }
      int rem = 4;
      int* row = idxout + ((size_t)b*NPTS + n0 + rep*4 + wv)*KNN;
      for (int sel=0; sel<KNN; ++sel){
        const int widx = wave_argmax_idx(s0, i0);
        if (lane == 0) row[sel] = widx;
        if ((widx >> 5) == lane){
          const float lastv = s0; const int lasti = i0;
          s0=s1;i0=i1; s1=s2;i1=i2; s2=s3;i2=i3;
          rem--;
          if (rem == 0){
            float nv = NEG_INF; int ni = 0x7fffffff;
            #pragma unroll 2
            for (int jb=0;jb<8;++jb){
              const int u = lane*8 + jb;
              const float4 q = *(const float4*)&dist[wv][(u ^ (lane&7))*4];
              const float qe[4] = {q.x, q.y, q.z, q.w};
              #pragma unroll
              for (int e=0;e<4;++e){
                const float vv = qe[e];
                const int   mi = lane*32 + jb*4 + e;
                const bool ok = (vv < lastv) || (vv == lastv && mi > lasti);
                if (ok && vv > nv){ nv = vv; ni = mi; }
              }
            }
            s0 = nv; i0 = ni; rem = 1;
          }
        }
      }
      __syncthreads();
    }
  }
}

// ---------------- prep_all: all weight preps + out5 zero, fused into one launch --------
__global__ __launch_bounds__(256) void prep_all_kernel(
    const float* __restrict__ w1, const float* __restrict__ w2,
    const float* __restrict__ w3, const float* __restrict__ w4,
    const float* __restrict__ w5,
    float* __restrict__ wnT1, float* __restrict__ wdT1,
    unsigned short* __restrict__ wn2, unsigned short* __restrict__ wd2,
    unsigned short* __restrict__ wn3, unsigned short* __restrict__ wd3,
    unsigned short* __restrict__ wn4, unsigned short* __restrict__ wd4,
    unsigned short* __restrict__ w5hi, unsigned short* __restrict__ w5lo,
    float* __restrict__ out5){
  int i = blockIdx.x*256 + threadIdx.x;
  if (i < 131072){                      // w5 split-bf16
    float4 v = *(const float4*)&w5[(size_t)i*4];
    unsigned short h0=bf16r(v.x), h1=bf16r(v.y), h2=bf16r(v.z), h3=bf16r(v.w);
    unsigned short l0=bf16r(v.x-bf2f(h0)), l1=bf16r(v.y-bf2f(h1)),
                   l2=bf16r(v.z-bf2f(h2)), l3=bf16r(v.w-bf2f(h3));
    *(uint2*)&w5hi[(size_t)i*4] = make_uint2((unsigned)h0|((unsigned)h1<<16), (unsigned)h2|((unsigned)h3<<16));
    *(uint2*)&w5lo[(size_t)i*4] = make_uint2((unsigned)l0|((unsigned)l1<<16), (unsigned)l2|((unsigned)l3<<16));
    return;
  }
  i -= 131072;
  if (i < 8192){ out5[i] = 0.f; return; }   // zero out5
  i -= 8192;
  if (i < 192){                         // layer-1 fp32 prep
    int c = i >> 6, o = i & 63;
    float a = w1[(size_t)o*6 + c];
    wnT1[c*64 + o] = a;
    wdT1[c*64 + o] = w1[(size_t)o*6 + 3 + c] - a;
    return;
  }
  i -= 192;
  if (i < 4096){                        // w2: O=64 C=64
    int c = i & 63, o = i >> 6;
    float a = w2[(size_t)o*128 + c];
    float d = w2[(size_t)o*128 + 64 + c] - a;
    wn2[i] = bf16r(a); wd2[i] = bf16r(d);
    return;
  }
  i -= 4096;
  if (i < 8192){                        // w3: O=128 C=64
    int c = i & 63, o = i >> 6;
    float a = w3[(size_t)o*128 + c];
    float d = w3[(size_t)o*128 + 64 + c] - a;
    wn3[i] = bf16r(a); wd3[i] = bf16r(d);
    return;
  }
  i -= 8192;
  if (i < 32768){                       // w4: O=256 C=128
    int c = i & 127, o = i >> 7;
    float a = w4[(size_t)o*256 + c];
    float d = w4[(size_t)o*256 + 128 + c] - a;
    wn4[i] = bf16r(a); wd4[i] = bf16r(d);
    return;
  }
}

// ---------------- xcat: concat x1T..x4T -> split-bf16 [b][n][512] ----------------
__global__ __launch_bounds__(256) void xcat_kernel(const float* __restrict__ x1T,
    const float* __restrict__ x2T, const float* __restrict__ x3T, const float* __restrict__ x4T,
    unsigned short* __restrict__ xhi, unsigned short* __restrict__ xlo){
  int i = blockIdx.x*blockDim.x + threadIdx.x;   // quad index over B*N*128
  if (i >= BATCH*NPTS*128) return;
  int q = i & 127, bn_ = i >> 7;
  int k = q*4;
  const float* src; int kk;
  if (k < 64)      { src = x1T + (size_t)bn_*64;  kk = k; }
  else if (k <128) { src = x2T + (size_t)bn_*64;  kk = k-64; }
  else if (k <256) { src = x3T + (size_t)bn_*128; kk = k-128; }
  else             { src = x4T + (size_t)bn_*256; kk = k-256; }
  float4 v = *(const float4*)&src[kk];
  unsigned short h0=bf16r(v.x), h1=bf16r(v.y), h2=bf16r(v.z), h3=bf16r(v.w);
  unsigned short l0=bf16r(v.x-bf2f(h0)), l1=bf16r(v.y-bf2f(h1)),
                 l2=bf16r(v.z-bf2f(h2)), l3=bf16r(v.w-bf2f(h3));
  *(uint2*)&xhi[(size_t)i*4] = make_uint2((unsigned)h0|((unsigned)h1<<16), (unsigned)h2|((unsigned)h3<<16));
  *(uint2*)&xlo[(size_t)i*4] = make_uint2((unsigned)l0|((unsigned)l1<<16), (unsigned)l2|((unsigned)l3<<16));
}

// ---------------- generic tiled transpose: in[R][Cc] -> out[Cc][R], per z-slice ----------------
__global__ __launch_bounds__(256) void transpose2d_kernel(const float* __restrict__ in,
    float* __restrict__ out, int R, int Cc){
  __shared__ float tile[32][33];
  const size_t boff = (size_t)blockIdx.z * (size_t)R * Cc;
  const int c0 = blockIdx.x*32, r0 = blockIdx.y*32;
  const int tx = threadIdx.x & 31, ty = threadIdx.x >> 5;
  #pragma unroll
  for (int j=0;j<4;++j){
    int r = ty*4 + j;
    tile[r][tx] = in[boff + (size_t)(r0+r)*Cc + c0 + tx];
  }
  __syncthreads();
  #pragma unroll
  for (int j=0;j<4;++j){
    int r = ty*4 + j;
    out[boff + (size_t)(c0+r)*R + r0 + tx] = tile[tx][r];
  }
}

// ---------------- x -> xT0 [N][3] + sq (layer-1 sqnorm fused) ----------------
__global__ void xt0sq_kernel(const float* __restrict__ x, float* __restrict__ xT0,
                             float* __restrict__ sq){
  int i = blockIdx.x*blockDim.x + threadIdx.x;
  if (i >= BATCH*NPTS) return;
  int b = i / NPTS, n = i - b*NPTS;
  const float* xb = x + (size_t)b*3*NPTS;
  float v0 = xb[n], v1 = xb[NPTS + n], v2 = xb[2*NPTS + n];
  float* o = xT0 + ((size_t)i)*3;
  o[0]=v0; o[1]=v1; o[2]=v2;
  float s = 0.f;
  s += v0*v0; s += v1*v1; s += v2*v2;
  sq[i] = s;
}

// ---------------- edge conv layer 1 (C=3, fp32): 4 points per block + fused sqnorm ------
__global__ __launch_bounds__(256) void edgeconv1_kernel(const float* __restrict__ xT0,
    const int* __restrict__ idx, const float* __restrict__ wnT, const float* __restrict__ wdT,
    const float* __restrict__ g, const float* __restrict__ bb, float* __restrict__ outT,
    float* __restrict__ sqout){
  const int b = blockIdx.y, n0 = blockIdx.x*4, t = threadIdx.x;
  __shared__ float nbr[4][KNN][3];
  __shared__ float ctr[4][3];
  __shared__ int   idxs[4][KNN];
  __shared__ float sqv[4][64];
  const float* xb = xT0 + (size_t)b*NPTS*3;
  if (t < 4*KNN) idxs[t/KNN][t%KNN] = idx[((size_t)b*NPTS + n0 + t/KNN)*KNN + (t%KNN)];
  if (t >= 128 && t < 140){ int i = t-128; ctr[i/3][i%3] = xb[(size_t)(n0 + i/3)*3 + i%3]; }
  __syncthreads();
  for (int i=t; i<4*KNN*3; i+=256){
    int p = i/(KNN*3), r = i - p*(KNN*3), k = r/3, c = r - k*3;
    nbr[p][k][c] = xb[(size_t)idxs[p][k]*3 + c];
  }
  __syncthreads();
  const int p = t >> 6, o = t & 63;
  const float wn0 = wnT[o], wn1 = wnT[64+o], wn2 = wnT[128+o];
  const float cst = ctr[p][0]*wdT[o] + ctr[p][1]*wdT[64+o] + ctr[p][2]*wdT[128+o];
  float best = NEG_INF;
  #pragma unroll
  for (int k=0;k<KNN;++k){
    float a = nbr[p][k][0]*wn0 + nbr[p][k][1]*wn1 + nbr[p][k][2]*wn2;
    best = fmaxf(best, a);
  }
  float vv = (best + cst) * bn_scale(g[o]) + bb[o];
  vv = fmaxf(vv, 0.f);
  outT[((size_t)b*NPTS + n0 + p)*64 + o] = vv;
  sqv[p][o] = vv;
  __syncthreads();
  if (t < 4){                           // exact ascending-o sum == sqnorm order
    float s = 0.f;
    for (int oo=0; oo<64; ++oo){ float q = sqv[t][oo]; s += q*q; }
    sqout[(size_t)b*NPTS + n0 + t] = s;
  }
}

// ---------------- edge conv MFMA (bf16): block = 4 points (+ optional fused sqnorm) ----
template<int C, int O, bool SQ>
__global__ __launch_bounds__(256) void edgeconv_mfma(const float* __restrict__ xT,
    const int* __restrict__ idx,
    const unsigned short* __restrict__ wn_bf, const unsigned short* __restrict__ wd_bf,
    const float* __restrict__ g, const float* __restrict__ bb, float* __restrict__ outT,
    float* __restrict__ sqout){
  constexpr int ROWS = 112;
  constexpr int CP   = C + 8;
  constexpr int KS   = C / 32;
  constexpr int NTW  = O / 64;
  __shared__ __align__(16) unsigned short A[ROWS][CP];
  __shared__ unsigned int res[4][O];
  __shared__ float cst_s[4][O];
  __shared__ int idxs[4][KNN];
  __shared__ float sqv[4][SQ ? O : 4];
  const int b = blockIdx.y, n0 = blockIdx.x*4, t = threadIdx.x;
  const float* xTb = xT + (size_t)b*NPTS*C;
  if (t < 4*KNN) idxs[t/KNN][t%KNN] = idx[((size_t)b*NPTS + n0 + t/KNN)*KNN + (t%KNN)];
  for (int i=t; i<4*O; i+=256) res[i/O][i & (O-1)] = 0u;
  __syncthreads();
  for (int i=t; i<ROWS*(C/4); i+=256){
    int r = i/(C/4), c4 = i - r*(C/4);
    float4 v = make_float4(0.f,0.f,0.f,0.f);
    if (r < 96){
      int p = r/24, kk = r - p*24;
      int src = idxs[p][kk < KNN ? kk : 0];
      v = *(const float4*)&xTb[(size_t)src*C + c4*4];
    } else if (r < 100){
      v = *(const float4*)&xTb[(size_t)(n0 + (r-96))*C + c4*4];
    }
    unsigned int lo = (unsigned int)bf16r(v.x) | ((unsigned int)bf16r(v.y) << 16);
    unsigned int hi = (unsigned int)bf16r(v.z) | ((unsigned int)bf16r(v.w) << 16);
    *(uint2*)&A[r][c4*4] = make_uint2(lo, hi);
  }
  __syncthreads();

  const int wv = t >> 6, l = t & 63;
  const int lane15 = l & 15, quad = l >> 4;
  bfrag Bn[NTW][KS];
  #pragma unroll
  for (int nt=0; nt<NTW; ++nt){
    const int col = (wv*NTW + nt)*16 + lane15;
    #pragma unroll
    for (int s=0; s<KS; ++s)
      Bn[nt][s] = *(const bfrag*)&wn_bf[(size_t)col*C + s*32 + quad*8];
  }
  #pragma unroll
  for (int mt=0; mt<7; ++mt){
    bfrag Af[KS];
    #pragma unroll
    for (int s=0; s<KS; ++s)
      Af[s] = *(const bfrag*)&A[mt*16 + lane15][s*32 + quad*8];
    if (mt < 6){
      const int rbase = mt*16 + quad*4;
      const int p = rbase / 24;
      #pragma unroll
      for (int nt=0; nt<NTW; ++nt){
        f32x4 acc = {0.f,0.f,0.f,0.f};
        #pragma unroll
        for (int s=0; s<KS; ++s)
          acc = __builtin_amdgcn_mfma_f32_16x16x32_bf16(Af[s], Bn[nt][s], acc, 0, 0, 0);
        float m = fmaxf(fmaxf(acc[0], acc[1]), fmaxf(acc[2], acc[3]));
        const int col = (wv*NTW + nt)*16 + lane15;
        atomicMax(&res[p][col], fenc(m));
      }
    } else {
      #pragma unroll
      for (int nt=0; nt<NTW; ++nt){
        const int col = (wv*NTW + nt)*16 + lane15;
        f32x4 acc = {0.f,0.f,0.f,0.f};
        #pragma unroll
        for (int s=0; s<KS; ++s){
          bfrag Bd = *(const bfrag*)&wd_bf[(size_t)col*C + s*32 + quad*8];
          acc = __builtin_amdgcn_mfma_f32_16x16x32_bf16(Af[s], Bd, acc, 0, 0, 0);
        }
        if (quad == 0){
          #pragma unroll
          for (int r=0;r<4;++r) cst_s[r][col] = acc[r];
        }
      }
    }
  }
  __syncthreads();
  for (int i=t; i<4*O; i+=256){
    int p = i/O, o = i - p*O;
    float mx = fdec(res[p][o]);
    float vv = (mx + cst_s[p][o]) * bn_scale(g[o]) + bb[o];
    vv = fmaxf(vv, 0.f);
    outT[((size_t)b*NPTS + n0 + p)*O + o] = vv;
    if (SQ) sqv[p][o] = vv;
  }
  if (SQ){
    __syncthreads();
    if (t < 4){
      float s = 0.f;
      for (int oo=0; oo<O; ++oo){ float q = sqv[t][oo]; s += q*q; }
      sqout[(size_t)b*NPTS + n0 + t] = s;
    }
  }
}

// ---------------- conv5 v4: o-tile 128 (halves A re-reads), split-bf16 MFMA + max -------
__global__ __launch_bounds__(256) void conv5_v4(const unsigned short* __restrict__ xhi,
    const unsigned short* __restrict__ xlo, const unsigned short* __restrict__ whi,
    const unsigned short* __restrict__ wlo, const float* __restrict__ g,
    const float* __restrict__ bb, float* __restrict__ out5){
  __shared__ __align__(16) unsigned short Ah_s[128*32];
  __shared__ __align__(16) unsigned short Al_s[128*32];
  __shared__ __align__(16) unsigned short Bh_s[128*32];
  __shared__ __align__(16) unsigned short Bl_s[128*32];
  const int t = threadIdx.x;
  const int row0 = blockIdx.x*128, o0 = blockIdx.y*128;
  const int b = row0 / NPTS;   // 128 | NPTS, so a block never straddles batches
  const int wv = t >> 6, l = t & 63, lane15 = l & 15, quad = l >> 4;
  const int ar = t >> 2, ac = (t & 3)*8;
  const unsigned short* gAh0 = xhi + (size_t)(row0 + ar)*512 + ac;
  const unsigned short* gAh1 = xhi + (size_t)(row0 + 64 + ar)*512 + ac;
  const unsigned short* gAl0 = xlo + (size_t)(row0 + ar)*512 + ac;
  const unsigned short* gAl1 = xlo + (size_t)(row0 + 64 + ar)*512 + ac;
  const unsigned short* gBh0 = whi + (size_t)(o0 + ar)*512 + ac;
  const unsigned short* gBh1 = whi + (size_t)(o0 + 64 + ar)*512 + ac;
  const unsigned short* gBl0 = wlo + (size_t)(o0 + ar)*512 + ac;
  const unsigned short* gBl1 = wlo + (size_t)(o0 + 64 + ar)*512 + ac;

  uint4 pf0 = *(const uint4*)gAh0;
  uint4 pf1 = *(const uint4*)gAh1;
  uint4 pf2 = *(const uint4*)gAl0;
  uint4 pf3 = *(const uint4*)gAl1;
  uint4 pf4 = *(const uint4*)gBh0;
  uint4 pf5 = *(const uint4*)gBh1;
  uint4 pf6 = *(const uint4*)gBl0;
  uint4 pf7 = *(const uint4*)gBl1;

  f32x4 acc[2][8];
  #pragma unroll
  for (int mt=0;mt<2;++mt)
    #pragma unroll
    for (int nt=0;nt<8;++nt) acc[mt][nt] = (f32x4){0.f,0.f,0.f,0.f};

  for (int ks=0; ks<16; ++ks){
    *(uint4*)&Ah_s[t*8]        = pf0;
    *(uint4*)&Ah_s[2048 + t*8] = pf1;
    *(uint4*)&Al_s[t*8]        = pf2;
    *(uint4*)&Al_s[2048 + t*8] = pf3;
    *(uint4*)&Bh_s[t*8]        = pf4;
    *(uint4*)&Bh_s[2048 + t*8] = pf5;
    *(uint4*)&Bl_s[t*8]        = pf6;
    *(uint4*)&Bl_s[2048 + t*8] = pf7;
    __syncthreads();
    if (ks < 15){
      const int koff = (ks+1)*32;
      pf0 = *(const uint4*)(gAh0 + koff);
      pf1 = *(const uint4*)(gAh1 + koff);
      pf2 = *(const uint4*)(gAl0 + koff);
      pf3 = *(const uint4*)(gAl1 + koff);
      pf4 = *(const uint4*)(gBh0 + koff);
      pf5 = *(const uint4*)(gBh1 + koff);
      pf6 = *(const uint4*)(gBl0 + koff);
      pf7 = *(const uint4*)(gBl1 + koff);
    }
    bfrag Afh[2], Afl[2];
    #pragma unroll
    for (int mt=0;mt<2;++mt){
      const int m = wv*32 + mt*16 + lane15;
      Afh[mt] = *(const bfrag*)&Ah_s[m*32 + quad*8];
      Afl[mt] = *(const bfrag*)&Al_s[m*32 + quad*8];
    }
    #pragma unroll
    for (int nt=0;nt<8;++nt){
      const int oc = nt*16 + lane15;
      const bfrag Bfh = *(const bfrag*)&Bh_s[oc*32 + quad*8];
      const bfrag Bfl = *(const bfrag*)&Bl_s[oc*32 + quad*8];
      #pragma unroll
      for (int mt=0;mt<2;++mt){
        acc[mt][nt] = __builtin_amdgcn_mfma_f32_16x16x32_bf16(Afh[mt], Bfh, acc[mt][nt], 0, 0, 0);
        acc[mt][nt] = __builtin_amdgcn_mfma_f32_16x16x32_bf16(Afl[mt], Bfh, acc[mt][nt], 0, 0, 0);
        acc[mt][nt] = __builtin_amdgcn_mfma_f32_16x16x32_bf16(Afh[mt], Bfl, acc[mt][nt], 0, 0, 0);
      }
    }
    __syncthreads();
  }
  #pragma unroll
  for (int nt=0;nt<8;++nt){
    float m = NEG_INF;
    #pragma unroll
    for (int mt=0;mt<2;++mt)
      #pragma unroll
      for (int r=0;r<4;++r) m = fmaxf(m, acc[mt][nt][r]);
    m = fmaxf(m, __shfl_xor(m, 16, 64));
    m = fmaxf(m, __shfl_xor(m, 32, 64));
    if (quad == 0){
      const int o = o0 + nt*16 + lane15;
      float vv = fmaxf(m * bn_scale(g[o]) + bb[o], 0.f);
      atomicMax((int*)&out5[(size_t)b*1024 + o], __float_as_int(vv));
    }
  }
}

// ---------------- FC layers: one wave per (b,o), coalesced lane-strided reads ----------
__global__ __launch_bounds__(256) void fc_wave_kernel(const float* __restrict__ in,
    const float* __restrict__ w, const float* __restrict__ g, const float* __restrict__ bb,
    float* __restrict__ out, int IN, int O){
  const int wid = (blockIdx.x*256 + threadIdx.x) >> 6;
  const int lane = threadIdx.x & 63;
  if (wid >= BATCH*O) return;
  const int b = wid / O, o = wid - b*O;
  const float* inb = in + (size_t)b*IN;
  const float* wo  = w + (size_t)o*IN;
  float s = 0.f;
  for (int c = lane; c < IN; c += 64) s += inb[c]*wo[c];
  s = wave_sum(s);
  if (lane == 0){
    if (g){ s = s*bn_scale(g[o]) + bb[o]; s = fmaxf(s, 0.f); }
    out[wid] = s;
  }
}

extern "C" void kernel_launch(void* const* d_in, const int* in_sizes, int n_in,
                              void* d_out, int out_size, void* d_ws, size_t ws_size,
                              hipStream_t stream){
  const float* x   = (const float*)d_in[0];
  const float* w1  = (const float*)d_in[1];
  const float* w2  = (const float*)d_in[2];
  const float* w3  = (const float*)d_in[3];
  const float* w4  = (const float*)d_in[4];
  const float* w5  = (const float*)d_in[5];
  const float* fw1 = (const float*)d_in[6];
  const float* fw2 = (const float*)d_in[7];
  const float* fw3 = (const float*)d_in[8];
  const float* g1 = (const float*)d_in[9];  const float* b1 = (const float*)d_in[10];
  const float* g2 = (const float*)d_in[11]; const float* b2 = (const float*)d_in[12];
  const float* g3 = (const float*)d_in[13]; const float* b3 = (const float*)d_in[14];
  const float* g4 = (const float*)d_in[15]; const float* b4 = (const float*)d_in[16];
  const float* g5 = (const float*)d_in[17]; const float* b5 = (const float*)d_in[18];
  const float* g6 = (const float*)d_in[19]; const float* b6 = (const float*)d_in[20];
  const float* g7 = (const float*)d_in[21]; const float* b7 = (const float*)d_in[22];

  float* ws = (float*)d_ws;
  size_t off = 0;
  // x1..x3 channel-major; this 4.19M-float region is later reused as xcat_lo
  float* x1  = ws + off; off += (size_t)BATCH*64*NPTS;
  float* x2  = ws + off; off += (size_t)BATCH*64*NPTS;
  float* x3  = ws + off; off += (size_t)BATCH*128*NPTS;
  unsigned short* xcat_lo = (unsigned short*)x1;           // alias: x1..x3 dead before xcat runs
  unsigned short* xcat_hi = (unsigned short*)(ws + off); off += (size_t)BATCH*256*NPTS;
  float* x1T = ws + off; off += (size_t)BATCH*64*NPTS;
  float* x2T = ws + off; off += (size_t)BATCH*64*NPTS;
  float* x3T = ws + off; off += (size_t)BATCH*128*NPTS;
  float* x4T = ws + off; off += (size_t)BATCH*256*NPTS;
  float* xT0 = ws + off; off += (size_t)BATCH*3*NPTS;
  float* sq  = ws + off; off += (size_t)BATCH*NPTS;
  int*  idx  = (int*)(ws + off); off += (size_t)BATCH*NPTS*KNN;
  float* out5 = ws + off; off += BATCH*1024;
  float* h6 = ws + off;   off += BATCH*512;
  float* h7 = ws + off;   off += BATCH*256;
  float* wnT1 = ws + off; off += 3*64;
  float* wdT1 = ws + off; off += 3*64;
  unsigned short* wn2 = (unsigned short*)(ws + off); off += 64*64/2;
  unsigned short* wd2 = (unsigned short*)(ws + off); off += 64*64/2;
  unsigned short* wn3 = (unsigned short*)(ws + off); off += 128*64/2;
  unsigned short* wd3 = (unsigned short*)(ws + off); off += 128*64/2;
  unsigned short* wn4 = (unsigned short*)(ws + off); off += 256*128/2;
  unsigned short* wd4 = (unsigned short*)(ws + off); off += 256*128/2;
  unsigned short* w5hi = (unsigned short*)(ws + off); off += 1024*512/2;
  unsigned short* w5lo = (unsigned short*)(ws + off); off += 1024*512/2;

  dim3 gridKNN8(NPTS/8, BATCH);
  dim3 gridEC(NPTS/4, BATCH);

  // all weight preps + out5 zero, fused (depends only on inputs)
  prep_all_kernel<<<721, 256, 0, stream>>>(w1, w2, w3, w4, w5, wnT1, wdT1,
                                           wn2, wd2, wn3, wd3, wn4, wd4,
                                           w5hi, w5lo, out5);
  // layer 1 (C=3 -> 64, fp32)
  xt0sq_kernel<<<64, 256, 0, stream>>>(x, xT0, sq);
  knn_kernel<3,8><<<gridKNN8, 256, 0, stream>>>(x, sq, idx);
  edgeconv1_kernel<<<gridEC, 256, 0, stream>>>(xT0, idx, wnT1, wdT1, g1, b1, x1T, sq);
  transpose2d_kernel<<<dim3(2,64,BATCH), 256, 0, stream>>>(x1T, x1, NPTS, 64);
  // layer 2 (C=64 -> 64, bf16 MFMA); writes sq(x2) for layer-3 knn
  knn_kernel<64,8><<<gridKNN8, 256, 0, stream>>>(x1, sq, idx);
  edgeconv_mfma<64,64,true><<<gridEC, 256, 0, stream>>>(x1T, idx, wn2, wd2, g2, b2, x2T, sq);
  transpose2d_kernel<<<dim3(2,64,BATCH), 256, 0, stream>>>(x2T, x2, NPTS, 64);
  // layer 3 (C=64 -> 128, bf16 MFMA); writes sq(x3) for layer-4 knn
  knn_kernel<64,8><<<gridKNN8, 256, 0, stream>>>(x2, sq, idx);
  edgeconv_mfma<64,128,true><<<gridEC, 256, 0, stream>>>(x2T, idx, wn3, wd3, g3, b3, x3T, sq);
  transpose2d_kernel<<<dim3(4,64,BATCH), 256, 0, stream>>>(x3T, x3, NPTS, 128);
  // layer 4 (C=128 -> 256, bf16 MFMA)
  knn_kernel<128,8><<<gridKNN8, 256, 0, stream>>>(x3, sq, idx);
  edgeconv_mfma<128,256,false><<<gridEC, 256, 0, stream>>>(x3T, idx, wn4, wd4, g4, b4, x4T, nullptr);
  // conv5 (split-bf16 MFMA, LDS-staged, o-tile 128) + global max over n
  xcat_kernel<<<(BATCH*NPTS*128)/256, 256, 0, stream>>>(x1T, x2T, x3T, x4T, xcat_hi, xcat_lo);
  conv5_v4<<<dim3(BATCH*NPTS/128, 8), 256, 0, stream>>>(xcat_hi, xcat_lo, w5hi, w5lo, g5, b5, out5);
  // FC head (wave-per-output, coalesced)
  fc_wave_kernel<<<(BATCH*512*64)/256, 256, 0, stream>>>(out5, fw1, g6, b6, h6, 1024, 512);
  fc_wave_kernel<<<(BATCH*256*64)/256, 256, 0, stream>>>(h6, fw2, g7, b7, h7, 512, 256);
  fc_wave_kernel<<<(BATCH*40*64 + 255)/256, 256, 0, stream>>>(h7, fw3, nullptr, nullptr, (float*)d_out, 256, 40);
}

// Round 9
// 678.488 us; speedup vs baseline: 1.1516x; 1.1516x over previous
//
#include <hip/hip_runtime.h>
#include <hip/hip_bf16.h>
#include <math.h>

#define BATCH 8
#define NPTS  2048
#define KNN   20
#define NEG_INF (-3.402823466e38f)

static __device__ __forceinline__ float bn_scale(float g){ return g * rsqrtf(1.0f + 1e-5f); }

// bf16 round-to-nearest-even
static __device__ __forceinline__ unsigned short bf16r(float f){
  unsigned int u = __float_as_uint(f);
  unsigned int r = (u + 0x7fffu + ((u >> 16) & 1u)) >> 16;
  return (unsigned short)r;
}
static __device__ __forceinline__ float bf2f(unsigned short h){
  return __uint_as_float((unsigned int)h << 16);
}
// ordered-int encode/decode for float max via atomicMax(uint)
static __device__ __forceinline__ unsigned int fenc(float f){
  unsigned int u = __float_as_uint(f);
  return (u & 0x80000000u) ? ~u : (u | 0x80000000u);
}
static __device__ __forceinline__ float fdec(unsigned int e){
  return __uint_as_float((e & 0x80000000u) ? (e & 0x7fffffffu) : ~e);
}

using bfrag = __attribute__((ext_vector_type(8))) short;  // 8 bf16 (4 VGPRs)
using f32x4 = __attribute__((ext_vector_type(4))) float;  // 4 fp32 acc
using f32x2 = __attribute__((ext_vector_type(2))) float;  // packed pair -> v_pk_fma_f32

// ---- wave argmax: value-only DPP max scan (6 fused steps), then index resolve ----
static __device__ __forceinline__ int wave_argmax_idx(float bv, int bi){
  float v = bv;
  #define AMAX_STEP(CTRL) { \
    int _t = __builtin_amdgcn_update_dpp(__float_as_int(NEG_INF), __float_as_int(v), \
                                         CTRL, 0xf, 0xf, false); \
    v = fmaxf(v, __int_as_float(_t)); }
  AMAX_STEP(0x111)  // row_shr:1
  AMAX_STEP(0x112)  // row_shr:2
  AMAX_STEP(0x114)  // row_shr:4
  AMAX_STEP(0x118)  // row_shr:8
  AMAX_STEP(0x142)  // row_bcast:15
  AMAX_STEP(0x143)  // row_bcast:31
  #undef AMAX_STEP
  const float vmax = __int_as_float(__builtin_amdgcn_readlane(__float_as_int(v), 63));
  unsigned long long m = __ballot(bv == vmax);           // >=1 lane set
  int widx = __builtin_amdgcn_readlane(bi, (int)__builtin_ctzll(m));
  if (m & (m - 1)){                                      // rare: cross-lane value tie
    unsigned long long r = m & (m - 1);
    while (r){
      int c = __builtin_amdgcn_readlane(bi, (int)__builtin_ctzll(r));
      widx = min(widx, c);
      r &= r - 1;
    }
  }
  return widx;
}
// ---- DPP wave sum (identity 0.0 injected); total broadcast from lane 63 ----
template<int CTRL>
static __device__ __forceinline__ float dpp_fadd(float v){
  int ov = __builtin_amdgcn_update_dpp(0, __float_as_int(v), CTRL, 0xf, 0xf, false);
  return v + __int_as_float(ov);
}
static __device__ __forceinline__ float wave_sum(float v){
  v = dpp_fadd<0x111>(v); v = dpp_fadd<0x112>(v);
  v = dpp_fadd<0x114>(v); v = dpp_fadd<0x118>(v);
  v = dpp_fadd<0x142>(v); v = dpp_fadd<0x143>(v);
  return __int_as_float(__builtin_amdgcn_readlane(__float_as_int(v), 63));
}

// ---------------- kNN v14 (round-4 proven): dist-only LDS (32 KB), ctr/sq wave-uniform
// global broadcasts, M=8, packed-f32 math, b128 swizzled scan, DPP selection ----------
template<int C, int M>
__global__ __launch_bounds__(256, 4) void knn_kernel(const float* __restrict__ X,
                                                     const float* __restrict__ sq,
                                                     int* __restrict__ idxout){
  const int b = blockIdx.y;
  const int n0 = blockIdx.x * M;
  const int t = threadIdx.x;
  __shared__ __align__(16) float dist[4][NPTS];   // the ONLY LDS: 32 KB
  const float* xb = X + (size_t)b*C*NPTS;

  const int m0 = t * 8;
  f32x2 acc2[M][4];
  #pragma unroll
  for (int i=0;i<M;++i)
    #pragma unroll
    for (int j=0;j<4;++j) acc2[i][j] = (f32x2){0.f, 0.f};
  #pragma unroll 2
  for (int c=0;c<C;++c){
    const float4 xa = *(const float4*)&xb[(size_t)c*NPTS + m0];
    const float4 xc = *(const float4*)&xb[(size_t)c*NPTS + m0 + 4];
    const f32x2 xm2[4] = {(f32x2){xa.x,xa.y}, (f32x2){xa.z,xa.w},
                          (f32x2){xc.x,xc.y}, (f32x2){xc.z,xc.w}};
    #pragma unroll
    for (int i4=0; i4<M/4; ++i4){
      const float4 cq = *(const float4*)&xb[(size_t)c*NPTS + n0 + i4*4];  // uniform 16B
      const float cvr[4] = {cq.x, cq.y, cq.z, cq.w};
      #pragma unroll
      for (int r=0;r<4;++r){
        const f32x2 cv2 = (f32x2){cvr[r], cvr[r]};
        #pragma unroll
        for (int j=0;j<4;++j) acc2[i4*4+r][j] += cv2*xm2[j];   // v_pk_fma_f32
      }
    }
  }
  {
    const float4 sa = *(const float4*)&sq[b*NPTS + m0];
    const float4 sb = *(const float4*)&sq[b*NPTS + m0 + 4];
    const f32x2 sm2[4] = {(f32x2){sa.x,sa.y}, (f32x2){sa.z,sa.w},
                          (f32x2){sb.x,sb.y}, (f32x2){sb.z,sb.w}};
    #pragma unroll
    for (int i4=0; i4<M/4; ++i4){
      const float4 sqc = *(const float4*)&sq[b*NPTS + n0 + i4*4];   // uniform
      const float sir[4] = {sqc.x, sqc.y, sqc.z, sqc.w};
      #pragma unroll
      for (int r=0;r<4;++r){
        const f32x2 si2 = (f32x2){sir[r], sir[r]};
        #pragma unroll
        for (int j=0;j<4;++j)
          acc2[i4*4+r][j] = (f32x2){2.f,2.f}*acc2[i4*4+r][j] - si2 - sm2[j];
      }
    }
  }

  const int wv = t >> 6, lane = t & 63;
  const int su0 = (((2*t)   ) ^ ((t>>2)&7)) * 4;
  const int su1 = (((2*t)+1 ) ^ ((t>>2)&7)) * 4;
  #pragma unroll
  for (int rep=0; rep<M/4; ++rep){
    #pragma unroll
    for (int i=0;i<4;++i){
      const int r = rep*4 + i;
      *(float4*)&dist[i][su0] = make_float4(acc2[r][0].x, acc2[r][0].y, acc2[r][1].x, acc2[r][1].y);
      *(float4*)&dist[i][su1] = make_float4(acc2[r][2].x, acc2[r][2].y, acc2[r][3].x, acc2[r][3].y);
    }
    __syncthreads();
    float s0=NEG_INF,s1=NEG_INF,s2=NEG_INF,s3=NEG_INF;
    int   i0=0x7fffffff,i1=0x7fffffff,i2=0x7fffffff,i3=0x7fffffff;
    #pragma unroll
    for (int jb=0;jb<8;++jb){
      const int u = lane*8 + jb;
      const float4 q = *(const float4*)&dist[wv][(u ^ (lane&7))*4];
      const float qe[4] = {q.x, q.y, q.z, q.w};
      #pragma unroll
      for (int e=0;e<4;++e){
        const float v = qe[e];
        const int   m = lane*32 + jb*4 + e;
        const bool b0 = v > s0, b1 = v > s1, b2 = v > s2, b3 = v > s3;
        const float n0_ = b0 ? v : s0;            const int q0 = b0 ? m : i0;
        const float n1_ = b0 ? s0 : (b1 ? v : s1); const int q1 = b0 ? i0 : (b1 ? m : i1);
        const float n2_ = b1 ? s1 : (b2 ? v : s2); const int q2 = b1 ? i1 : (b2 ? m : i2);
        const float n3_ = b2 ? s2 : (b3 ? v : s3); const int q3 = b2 ? i2 : (b3 ? m : i3);
        s0=n0_;s1=n1_;s2=n2_;s3=n3_; i0=q0;i1=q1;i2=q2;i3=q3;
      }
    }
    int rem = 4;
    int* row = idxout + ((size_t)b*NPTS + n0 + rep*4 + wv)*KNN;
    for (int sel=0; sel<KNN; ++sel){
      const int widx = wave_argmax_idx(s0, i0);
      if (lane == 0) row[sel] = widx;
      if ((widx >> 5) == lane){
        const float lastv = s0; const int lasti = i0;
        s0=s1;i0=i1; s1=s2;i1=i2; s2=s3;i2=i3;
        rem--;
        if (rem == 0){
          float nv = NEG_INF; int ni = 0x7fffffff;
          #pragma unroll 2
          for (int jb=0;jb<8;++jb){
            const int u = lane*8 + jb;
            const float4 q = *(const float4*)&dist[wv][(u ^ (lane&7))*4];
            const float qe[4] = {q.x, q.y, q.z, q.w};
            #pragma unroll
            for (int e=0;e<4;++e){
              const float vv = qe[e];
              const int   mi = lane*32 + jb*4 + e;
              const bool ok = (vv < lastv) || (vv == lastv && mi > lasti);
              if (ok && vv > nv){ nv = vv; ni = mi; }
            }
          }
          s0 = nv; i0 = ni; rem = 1;
        }
      }
    }
    __syncthreads();
  }
}

// ---------------- prep_all: all weight preps + out5 zero, fused into one launch --------
__global__ __launch_bounds__(256) void prep_all_kernel(
    const float* __restrict__ w1, const float* __restrict__ w2,
    const float* __restrict__ w3, const float* __restrict__ w4,
    const float* __restrict__ w5,
    float* __restrict__ wnT1, float* __restrict__ wdT1,
    unsigned short* __restrict__ wn2, unsigned short* __restrict__ wd2,
    unsigned short* __restrict__ wn3, unsigned short* __restrict__ wd3,
    unsigned short* __restrict__ wn4, unsigned short* __restrict__ wd4,
    unsigned short* __restrict__ w5hi, unsigned short* __restrict__ w5lo,
    float* __restrict__ out5){
  int i = blockIdx.x*256 + threadIdx.x;
  if (i < 131072){                      // w5 split-bf16
    float4 v = *(const float4*)&w5[(size_t)i*4];
    unsigned short h0=bf16r(v.x), h1=bf16r(v.y), h2=bf16r(v.z), h3=bf16r(v.w);
    unsigned short l0=bf16r(v.x-bf2f(h0)), l1=bf16r(v.y-bf2f(h1)),
                   l2=bf16r(v.z-bf2f(h2)), l3=bf16r(v.w-bf2f(h3));
    *(uint2*)&w5hi[(size_t)i*4] = make_uint2((unsigned)h0|((unsigned)h1<<16), (unsigned)h2|((unsigned)h3<<16));
    *(uint2*)&w5lo[(size_t)i*4] = make_uint2((unsigned)l0|((unsigned)l1<<16), (unsigned)l2|((unsigned)l3<<16));
    return;
  }
  i -= 131072;
  if (i < 8192){ out5[i] = 0.f; return; }   // zero out5
  i -= 8192;
  if (i < 192){                         // layer-1 fp32 prep
    int c = i >> 6, o = i & 63;
    float a = w1[(size_t)o*6 + c];
    wnT1[c*64 + o] = a;
    wdT1[c*64 + o] = w1[(size_t)o*6 + 3 + c] - a;
    return;
  }
  i -= 192;
  if (i < 4096){                        // w2: O=64 C=64
    int c = i & 63, o = i >> 6;
    float a = w2[(size_t)o*128 + c];
    float d = w2[(size_t)o*128 + 64 + c] - a;
    wn2[i] = bf16r(a); wd2[i] = bf16r(d);
    return;
  }
  i -= 4096;
  if (i < 8192){                        // w3: O=128 C=64
    int c = i & 63, o = i >> 6;
    float a = w3[(size_t)o*128 + c];
    float d = w3[(size_t)o*128 + 64 + c] - a;
    wn3[i] = bf16r(a); wd3[i] = bf16r(d);
    return;
  }
  i -= 8192;
  if (i < 32768){                       // w4: O=256 C=128
    int c = i & 127, o = i >> 7;
    float a = w4[(size_t)o*256 + c];
    float d = w4[(size_t)o*256 + 128 + c] - a;
    wn4[i] = bf16r(a); wd4[i] = bf16r(d);
    return;
  }
}

// ---------------- generic tiled transpose: in[R][Cc] -> out[Cc][R], per z-slice ----------------
__global__ __launch_bounds__(256) void transpose2d_kernel(const float* __restrict__ in,
    float* __restrict__ out, int R, int Cc){
  __shared__ float tile[32][33];
  const size_t boff = (size_t)blockIdx.z * (size_t)R * Cc;
  const int c0 = blockIdx.x*32, r0 = blockIdx.y*32;
  const int tx = threadIdx.x & 31, ty = threadIdx.x >> 5;
  #pragma unroll
  for (int j=0;j<4;++j){
    int r = ty*4 + j;
    tile[r][tx] = in[boff + (size_t)(r0+r)*Cc + c0 + tx];
  }
  __syncthreads();
  #pragma unroll
  for (int j=0;j<4;++j){
    int r = ty*4 + j;
    out[boff + (size_t)(c0+r)*R + r0 + tx] = tile[tx][r];
  }
}

// ---------------- x -> xT0 [N][3] + sq (layer-1 sqnorm fused) ----------------
__global__ void xt0sq_kernel(const float* __restrict__ x, float* __restrict__ xT0,
                             float* __restrict__ sq){
  int i = blockIdx.x*blockDim.x + threadIdx.x;
  if (i >= BATCH*NPTS) return;
  int b = i / NPTS, n = i - b*NPTS;
  const float* xb = x + (size_t)b*3*NPTS;
  float v0 = xb[n], v1 = xb[NPTS + n], v2 = xb[2*NPTS + n];
  float* o = xT0 + ((size_t)i)*3;
  o[0]=v0; o[1]=v1; o[2]=v2;
  float s = 0.f;
  s += v0*v0; s += v1*v1; s += v2*v2;
  sq[i] = s;
}

// ---------------- edge conv layer 1 (C=3, fp32) + fused sqnorm + xcat split write ------
__global__ __launch_bounds__(256) void edgeconv1_kernel(const float* __restrict__ xT0,
    const int* __restrict__ idx, const float* __restrict__ wnT, const float* __restrict__ wdT,
    const float* __restrict__ g, const float* __restrict__ bb, float* __restrict__ outT,
    float* __restrict__ sqout, unsigned short* __restrict__ xhi,
    unsigned short* __restrict__ xlo){
  const int b = blockIdx.y, n0 = blockIdx.x*4, t = threadIdx.x;
  __shared__ float nbr[4][KNN][3];
  __shared__ float ctr[4][3];
  __shared__ int   idxs[4][KNN];
  __shared__ float sqv[4][64];
  const float* xb = xT0 + (size_t)b*NPTS*3;
  if (t < 4*KNN) idxs[t/KNN][t%KNN] = idx[((size_t)b*NPTS + n0 + t/KNN)*KNN + (t%KNN)];
  if (t >= 128 && t < 140){ int i = t-128; ctr[i/3][i%3] = xb[(size_t)(n0 + i/3)*3 + i%3]; }
  __syncthreads();
  for (int i=t; i<4*KNN*3; i+=256){
    int p = i/(KNN*3), r = i - p*(KNN*3), k = r/3, c = r - k*3;
    nbr[p][k][c] = xb[(size_t)idxs[p][k]*3 + c];
  }
  __syncthreads();
  const int p = t >> 6, o = t & 63;
  const float wn0 = wnT[o], wn1 = wnT[64+o], wn2 = wnT[128+o];
  const float cst = ctr[p][0]*wdT[o] + ctr[p][1]*wdT[64+o] + ctr[p][2]*wdT[128+o];
  float best = NEG_INF;
  #pragma unroll
  for (int k=0;k<KNN;++k){
    float a = nbr[p][k][0]*wn0 + nbr[p][k][1]*wn1 + nbr[p][k][2]*wn2;
    best = fmaxf(best, a);
  }
  float vv = (best + cst) * bn_scale(g[o]) + bb[o];
  vv = fmaxf(vv, 0.f);
  const size_t bn_ = (size_t)b*NPTS + n0 + p;
  outT[bn_*64 + o] = vv;
  { unsigned short h = bf16r(vv);
    xhi[bn_*512 + o] = h;
    xlo[bn_*512 + o] = bf16r(vv - bf2f(h)); }
  sqv[p][o] = vv;
  __syncthreads();
  if (t < 4){                           // exact ascending-o sum == sqnorm order
    float s = 0.f;
    for (int oo=0; oo<64; ++oo){ float q = sqv[t][oo]; s += q*q; }
    sqout[(size_t)b*NPTS + n0 + t] = s;
  }
}

// ---------------- edge conv MFMA (bf16): block = 4 points --------------------------------
// SQ: fused sqnorm for next layer's knn; XOFF: xcat slice offset; WF: write float outT
template<int C, int O, bool SQ, int XOFF, bool WF>
__global__ __launch_bounds__(256) void edgeconv_mfma(const float* __restrict__ xT,
    const int* __restrict__ idx,
    const unsigned short* __restrict__ wn_bf, const unsigned short* __restrict__ wd_bf,
    const float* __restrict__ g, const float* __restrict__ bb, float* __restrict__ outT,
    float* __restrict__ sqout, unsigned short* __restrict__ xhi,
    unsigned short* __restrict__ xlo){
  constexpr int ROWS = 112;
  constexpr int CP   = C + 8;
  constexpr int KS   = C / 32;
  constexpr int NTW  = O / 64;
  __shared__ __align__(16) unsigned short A[ROWS][CP];
  __shared__ unsigned int res[4][O];
  __shared__ float cst_s[4][O];
  __shared__ int idxs[4][KNN];
  __shared__ float sqv[4][SQ ? O : 4];
  const int b = blockIdx.y, n0 = blockIdx.x*4, t = threadIdx.x;
  const float* xTb = xT + (size_t)b*NPTS*C;
  if (t < 4*KNN) idxs[t/KNN][t%KNN] = idx[((size_t)b*NPTS + n0 + t/KNN)*KNN + (t%KNN)];
  for (int i=t; i<4*O; i+=256) res[i/O][i & (O-1)] = 0u;
  __syncthreads();
  for (int i=t; i<ROWS*(C/4); i+=256){
    int r = i/(C/4), c4 = i - r*(C/4);
    float4 v = make_float4(0.f,0.f,0.f,0.f);
    if (r < 96){
      int p = r/24, kk = r - p*24;
      int src = idxs[p][kk < KNN ? kk : 0];
      v = *(const float4*)&xTb[(size_t)src*C + c4*4];
    } else if (r < 100){
      v = *(const float4*)&xTb[(size_t)(n0 + (r-96))*C + c4*4];
    }
    unsigned int lo = (unsigned int)bf16r(v.x) | ((unsigned int)bf16r(v.y) << 16);
    unsigned int hi = (unsigned int)bf16r(v.z) | ((unsigned int)bf16r(v.w) << 16);
    *(uint2*)&A[r][c4*4] = make_uint2(lo, hi);
  }
  __syncthreads();

  const int wv = t >> 6, l = t & 63;
  const int lane15 = l & 15, quad = l >> 4;
  bfrag Bn[NTW][KS];
  #pragma unroll
  for (int nt=0; nt<NTW; ++nt){
    const int col = (wv*NTW + nt)*16 + lane15;
    #pragma unroll
    for (int s=0; s<KS; ++s)
      Bn[nt][s] = *(const bfrag*)&wn_bf[(size_t)col*C + s*32 + quad*8];
  }
  #pragma unroll
  for (int mt=0; mt<7; ++mt){
    bfrag Af[KS];
    #pragma unroll
    for (int s=0; s<KS; ++s)
      Af[s] = *(const bfrag*)&A[mt*16 + lane15][s*32 + quad*8];
    if (mt < 6){
      const int rbase = mt*16 + quad*4;
      const int p = rbase / 24;
      #pragma unroll
      for (int nt=0; nt<NTW; ++nt){
        f32x4 acc = {0.f,0.f,0.f,0.f};
        #pragma unroll
        for (int s=0; s<KS; ++s)
          acc = __builtin_amdgcn_mfma_f32_16x16x32_bf16(Af[s], Bn[nt][s], acc, 0, 0, 0);
        float m = fmaxf(fmaxf(acc[0], acc[1]), fmaxf(acc[2], acc[3]));
        const int col = (wv*NTW + nt)*16 + lane15;
        atomicMax(&res[p][col], fenc(m));
      }
    } else {
      #pragma unroll
      for (int nt=0; nt<NTW; ++nt){
        const int col = (wv*NTW + nt)*16 + lane15;
        f32x4 acc = {0.f,0.f,0.f,0.f};
        #pragma unroll
        for (int s=0; s<KS; ++s){
          bfrag Bd = *(const bfrag*)&wd_bf[(size_t)col*C + s*32 + quad*8];
          acc = __builtin_amdgcn_mfma_f32_16x16x32_bf16(Af[s], Bd, acc, 0, 0, 0);
        }
        if (quad == 0){
          #pragma unroll
          for (int r=0;r<4;++r) cst_s[r][col] = acc[r];
        }
      }
    }
  }
  __syncthreads();
  for (int i=t; i<4*O; i+=256){
    int p = i/O, o = i - p*O;
    float mx = fdec(res[p][o]);
    float vv = (mx + cst_s[p][o]) * bn_scale(g[o]) + bb[o];
    vv = fmaxf(vv, 0.f);
    const size_t bn_ = (size_t)b*NPTS + n0 + p;
    if (WF) outT[bn_*O + o] = vv;
    { unsigned short h = bf16r(vv);          // xcat slice fused (bit-exact vs old xcat)
      xhi[bn_*512 + XOFF + o] = h;
      xlo[bn_*512 + XOFF + o] = bf16r(vv - bf2f(h)); }
    if (SQ) sqv[p][o] = vv;
  }
  if (SQ){
    __syncthreads();
    if (t < 4){
      float s = 0.f;
      for (int oo=0; oo<O; ++oo){ float q = sqv[t][oo]; s += q*q; }
      sqout[(size_t)b*NPTS + n0 + t] = s;
    }
  }
}

// ---------------- conv5 v3 (round-4 proven): LDS-staged split-bf16 MFMA GEMM + max -----
__global__ __launch_bounds__(256) void conv5_v3(const unsigned short* __restrict__ xhi,
    const unsigned short* __restrict__ xlo, const unsigned short* __restrict__ whi,
    const unsigned short* __restrict__ wlo, const float* __restrict__ g,
    const float* __restrict__ bb, float* __restrict__ out5){
  __shared__ __align__(16) unsigned short Ah_s[128*32];
  __shared__ __align__(16) unsigned short Al_s[128*32];
  __shared__ __align__(16) unsigned short Bh_s[64*32];
  __shared__ __align__(16) unsigned short Bl_s[64*32];
  const int t = threadIdx.x;
  const int row0 = blockIdx.x*128, o0 = blockIdx.y*64;
  const int b = row0 / NPTS;   // 128 | NPTS, so a block never straddles batches
  const int wv = t >> 6, l = t & 63, lane15 = l & 15, quad = l >> 4;
  const int ar = t >> 2, ac = (t & 3)*8;
  const unsigned short* gAh0 = xhi + (size_t)(row0 + ar)*512 + ac;
  const unsigned short* gAh1 = xhi + (size_t)(row0 + 64 + ar)*512 + ac;
  const unsigned short* gAl0 = xlo + (size_t)(row0 + ar)*512 + ac;
  const unsigned short* gAl1 = xlo + (size_t)(row0 + 64 + ar)*512 + ac;
  const unsigned short* gBh  = whi + (size_t)(o0 + ar)*512 + ac;
  const unsigned short* gBl  = wlo + (size_t)(o0 + ar)*512 + ac;

  uint4 pf0 = *(const uint4*)gAh0;
  uint4 pf1 = *(const uint4*)gAh1;
  uint4 pf2 = *(const uint4*)gAl0;
  uint4 pf3 = *(const uint4*)gAl1;
  uint4 pf4 = *(const uint4*)gBh;
  uint4 pf5 = *(const uint4*)gBl;

  f32x4 acc[2][4];
  #pragma unroll
  for (int mt=0;mt<2;++mt)
    #pragma unroll
    for (int nt=0;nt<4;++nt) acc[mt][nt] = (f32x4){0.f,0.f,0.f,0.f};

  for (int ks=0; ks<16; ++ks){
    *(uint4*)&Ah_s[t*8]        = pf0;
    *(uint4*)&Ah_s[2048 + t*8] = pf1;
    *(uint4*)&Al_s[t*8]        = pf2;
    *(uint4*)&Al_s[2048 + t*8] = pf3;
    *(uint4*)&Bh_s[t*8]        = pf4;
    *(uint4*)&Bl_s[t*8]        = pf5;
    __syncthreads();
    if (ks < 15){
      const int koff = (ks+1)*32;
      pf0 = *(const uint4*)(gAh0 + koff);
      pf1 = *(const uint4*)(gAh1 + koff);
      pf2 = *(const uint4*)(gAl0 + koff);
      pf3 = *(const uint4*)(gAl1 + koff);
      pf4 = *(const uint4*)(gBh  + koff);
      pf5 = *(const uint4*)(gBl  + koff);
    }
    bfrag Afh[2], Afl[2], Bfh[4], Bfl[4];
    #pragma unroll
    for (int mt=0;mt<2;++mt){
      const int m = wv*32 + mt*16 + lane15;
      Afh[mt] = *(const bfrag*)&Ah_s[m*32 + quad*8];
      Afl[mt] = *(const bfrag*)&Al_s[m*32 + quad*8];
    }
    #pragma unroll
    for (int nt=0;nt<4;++nt){
      const int oc = nt*16 + lane15;
      Bfh[nt] = *(const bfrag*)&Bh_s[oc*32 + quad*8];
      Bfl[nt] = *(const bfrag*)&Bl_s[oc*32 + quad*8];
    }
    #pragma unroll
    for (int mt=0;mt<2;++mt)
      #pragma unroll
      for (int nt=0;nt<4;++nt){
        acc[mt][nt] = __builtin_amdgcn_mfma_f32_16x16x32_bf16(Afh[mt], Bfh[nt], acc[mt][nt], 0, 0, 0);
        acc[mt][nt] = __builtin_amdgcn_mfma_f32_16x16x32_bf16(Afl[mt], Bfh[nt], acc[mt][nt], 0, 0, 0);
        acc[mt][nt] = __builtin_amdgcn_mfma_f32_16x16x32_bf16(Afh[mt], Bfl[nt], acc[mt][nt], 0, 0, 0);
      }
    __syncthreads();
  }
  #pragma unroll
  for (int nt=0;nt<4;++nt){
    float m = NEG_INF;
    #pragma unroll
    for (int mt=0;mt<2;++mt)
      #pragma unroll
      for (int r=0;r<4;++r) m = fmaxf(m, acc[mt][nt][r]);
    m = fmaxf(m, __shfl_xor(m, 16, 64));
    m = fmaxf(m, __shfl_xor(m, 32, 64));
    if (quad == 0){
      const int o = o0 + nt*16 + lane15;
      float vv = fmaxf(m * bn_scale(g[o]) + bb[o], 0.f);
      atomicMax((int*)&out5[(size_t)b*1024 + o], __float_as_int(vv));
    }
  }
}

// ---------------- FC layers: one wave per (b,o), coalesced lane-strided reads ----------
__global__ __launch_bounds__(256) void fc_wave_kernel(const float* __restrict__ in,
    const float* __restrict__ w, const float* __restrict__ g, const float* __restrict__ bb,
    float* __restrict__ out, int IN, int O){
  const int wid = (blockIdx.x*256 + threadIdx.x) >> 6;
  const int lane = threadIdx.x & 63;
  if (wid >= BATCH*O) return;
  const int b = wid / O, o = wid - b*O;
  const float* inb = in + (size_t)b*IN;
  const float* wo  = w + (size_t)o*IN;
  float s = 0.f;
  for (int c = lane; c < IN; c += 64) s += inb[c]*wo[c];
  s = wave_sum(s);
  if (lane == 0){
    if (g){ s = s*bn_scale(g[o]) + bb[o]; s = fmaxf(s, 0.f); }
    out[wid] = s;
  }
}

extern "C" void kernel_launch(void* const* d_in, const int* in_sizes, int n_in,
                              void* d_out, int out_size, void* d_ws, size_t ws_size,
                              hipStream_t stream){
  const float* x   = (const float*)d_in[0];
  const float* w1  = (const float*)d_in[1];
  const float* w2  = (const float*)d_in[2];
  const float* w3  = (const float*)d_in[3];
  const float* w4  = (const float*)d_in[4];
  const float* w5  = (const float*)d_in[5];
  const float* fw1 = (const float*)d_in[6];
  const float* fw2 = (const float*)d_in[7];
  const float* fw3 = (const float*)d_in[8];
  const float* g1 = (const float*)d_in[9];  const float* b1 = (const float*)d_in[10];
  const float* g2 = (const float*)d_in[11]; const float* b2 = (const float*)d_in[12];
  const float* g3 = (const float*)d_in[13]; const float* b3 = (const float*)d_in[14];
  const float* g4 = (const float*)d_in[15]; const float* b4 = (const float*)d_in[16];
  const float* g5 = (const float*)d_in[17]; const float* b5 = (const float*)d_in[18];
  const float* g6 = (const float*)d_in[19]; const float* b6 = (const float*)d_in[20];
  const float* g7 = (const float*)d_in[21]; const float* b7 = (const float*)d_in[22];

  float* ws = (float*)d_ws;
  size_t off = 0;
  // x1..x3 channel-major (knn inputs)
  float* x1  = ws + off; off += (size_t)BATCH*64*NPTS;
  float* x2  = ws + off; off += (size_t)BATCH*64*NPTS;
  float* x3  = ws + off; off += (size_t)BATCH*128*NPTS;
  unsigned short* xcat_hi = (unsigned short*)(ws + off); off += (size_t)BATCH*256*NPTS;
  float* x1T = ws + off; off += (size_t)BATCH*64*NPTS;
  float* x2T = ws + off; off += (size_t)BATCH*64*NPTS;
  float* x3T = ws + off; off += (size_t)BATCH*128*NPTS;
  // old x4T slot now hosts xcat_lo (layer-4 writes its xcat slice directly)
  unsigned short* xcat_lo = (unsigned short*)(ws + off); off += (size_t)BATCH*256*NPTS;
  float* xT0 = ws + off; off += (size_t)BATCH*3*NPTS;
  float* sq  = ws + off; off += (size_t)BATCH*NPTS;
  int*  idx  = (int*)(ws + off); off += (size_t)BATCH*NPTS*KNN;
  float* out5 = ws + off; off += BATCH*1024;
  float* h6 = ws + off;   off += BATCH*512;
  float* h7 = ws + off;   off += BATCH*256;
  float* wnT1 = ws + off; off += 3*64;
  float* wdT1 = ws + off; off += 3*64;
  unsigned short* wn2 = (unsigned short*)(ws + off); off += 64*64/2;
  unsigned short* wd2 = (unsigned short*)(ws + off); off += 64*64/2;
  unsigned short* wn3 = (unsigned short*)(ws + off); off += 128*64/2;
  unsigned short* wd3 = (unsigned short*)(ws + off); off += 128*64/2;
  unsigned short* wn4 = (unsigned short*)(ws + off); off += 256*128/2;
  unsigned short* wd4 = (unsigned short*)(ws + off); off += 256*128/2;
  unsigned short* w5hi = (unsigned short*)(ws + off); off += 1024*512/2;
  unsigned short* w5lo = (unsigned short*)(ws + off); off += 1024*512/2;

  dim3 gridKNN8(NPTS/8, BATCH);
  dim3 gridEC(NPTS/4, BATCH);

  // all weight preps + out5 zero, fused (depends only on inputs)
  prep_all_kernel<<<721, 256, 0, stream>>>(w1, w2, w3, w4, w5, wnT1, wdT1,
                                           wn2, wd2, wn3, wd3, wn4, wd4,
                                           w5hi, w5lo, out5);
  // layer 1 (C=3 -> 64, fp32)
  xt0sq_kernel<<<64, 256, 0, stream>>>(x, xT0, sq);
  knn_kernel<3,8><<<gridKNN8, 256, 0, stream>>>(x, sq, idx);
  edgeconv1_kernel<<<gridEC, 256, 0, stream>>>(xT0, idx, wnT1, wdT1, g1, b1, x1T, sq,
                                               xcat_hi, xcat_lo);
  transpose2d_kernel<<<dim3(2,64,BATCH), 256, 0, stream>>>(x1T, x1, NPTS, 64);
  // layer 2 (C=64 -> 64, bf16 MFMA); writes sq(x2) + xcat slice [64:128)
  knn_kernel<64,8><<<gridKNN8, 256, 0, stream>>>(x1, sq, idx);
  edgeconv_mfma<64,64,true,64,true><<<gridEC, 256, 0, stream>>>(x1T, idx, wn2, wd2, g2, b2,
                                                                x2T, sq, xcat_hi, xcat_lo);
  transpose2d_kernel<<<dim3(2,64,BATCH), 256, 0, stream>>>(x2T, x2, NPTS, 64);
  // layer 3 (C=64 -> 128, bf16 MFMA); writes sq(x3) + xcat slice [128:256)
  knn_kernel<64,8><<<gridKNN8, 256, 0, stream>>>(x2, sq, idx);
  edgeconv_mfma<64,128,true,128,true><<<gridEC, 256, 0, stream>>>(x2T, idx, wn3, wd3, g3, b3,
                                                                  x3T, sq, xcat_hi, xcat_lo);
  transpose2d_kernel<<<dim3(4,64,BATCH), 256, 0, stream>>>(x3T, x3, NPTS, 128);
  // layer 4 (C=128 -> 256, bf16 MFMA); writes ONLY xcat slice [256:512) (no float x4T)
  knn_kernel<128,8><<<gridKNN8, 256, 0, stream>>>(x3, sq, idx);
  edgeconv_mfma<128,256,false,256,false><<<gridEC, 256, 0, stream>>>(x3T, idx, wn4, wd4, g4, b4,
                                                                     nullptr, nullptr,
                                                                     xcat_hi, xcat_lo);
  // conv5 (split-bf16 MFMA, LDS-staged) + global max over n  (xcat kernel deleted)
  conv5_v3<<<dim3(BATCH*NPTS/128, 16), 256, 0, stream>>>(xcat_hi, xcat_lo, w5hi, w5lo, g5, b5, out5);
  // FC head (wave-per-output, coalesced)
  fc_wave_kernel<<<(BATCH*512*64)/256, 256, 0, stream>>>(out5, fw1, g6, b6, h6, 1024, 512);
  fc_wave_kernel<<<(BATCH*256*64)/256, 256, 0, stream>>>(h6, fw2, g7, b7, h7, 512, 256);
  fc_wave_kernel<<<(BATCH*40*64 + 255)/256, 256, 0, stream>>>(h7, fw3, nullptr, nullptr, (float*)d_out, 256, 40);
}

// Round 10
// 662.052 us; speedup vs baseline: 1.1802x; 1.0248x over previous
//
#include <hip/hip_runtime.h>
#include <hip/hip_bf16.h>
#include <math.h>

#define BATCH 8
#define NPTS  2048
#define KNN   20
#define NEG_INF (-3.402823466e38f)

static __device__ __forceinline__ float bn_scale(float g){ return g * rsqrtf(1.0f + 1e-5f); }

// bf16 round-to-nearest-even
static __device__ __forceinline__ unsigned short bf16r(float f){
  unsigned int u = __float_as_uint(f);
  unsigned int r = (u + 0x7fffu + ((u >> 16) & 1u)) >> 16;
  return (unsigned short)r;
}
static __device__ __forceinline__ float bf2f(unsigned short h){
  return __uint_as_float((unsigned int)h << 16);
}
// ordered-int encode/decode for float max via atomicMax(uint)
static __device__ __forceinline__ unsigned int fenc(float f){
  unsigned int u = __float_as_uint(f);
  return (u & 0x80000000u) ? ~u : (u | 0x80000000u);
}
static __device__ __forceinline__ float fdec(unsigned int e){
  return __uint_as_float((e & 0x80000000u) ? (e & 0x7fffffffu) : ~e);
}

using bfrag = __attribute__((ext_vector_type(8))) short;  // 8 bf16 (4 VGPRs)
using f32x4 = __attribute__((ext_vector_type(4))) float;  // 4 fp32 acc
using f32x2 = __attribute__((ext_vector_type(2))) float;  // packed pair -> v_pk_fma_f32

// ---- wave argmax v3: value-only DPP max scan, ballot resolve. Tie loop REMOVED:
// lanes own disjoint ascending idx chunks, so min idx among value-tied heads is always
// the lowest set lane (ctz) -- provably identical to the old min-loop. ----
static __device__ __forceinline__ int wave_argmax_idx(float bv, int bi){
  float v = bv;
  #define AMAX_STEP(CTRL) { \
    int _t = __builtin_amdgcn_update_dpp(__float_as_int(NEG_INF), __float_as_int(v), \
                                         CTRL, 0xf, 0xf, false); \
    v = fmaxf(v, __int_as_float(_t)); }
  AMAX_STEP(0x111)  // row_shr:1
  AMAX_STEP(0x112)  // row_shr:2
  AMAX_STEP(0x114)  // row_shr:4
  AMAX_STEP(0x118)  // row_shr:8
  AMAX_STEP(0x142)  // row_bcast:15
  AMAX_STEP(0x143)  // row_bcast:31
  #undef AMAX_STEP
  const float vmax = __int_as_float(__builtin_amdgcn_readlane(__float_as_int(v), 63));
  unsigned long long m = __ballot(bv == vmax);           // >=1 lane set
  return __builtin_amdgcn_readlane(bi, (int)__builtin_ctzll(m));
}
// ---- DPP wave sum (identity 0.0 injected); total broadcast from lane 63 ----
template<int CTRL>
static __device__ __forceinline__ float dpp_fadd(float v){
  int ov = __builtin_amdgcn_update_dpp(0, __float_as_int(v), CTRL, 0xf, 0xf, false);
  return v + __int_as_float(ov);
}
static __device__ __forceinline__ float wave_sum(float v){
  v = dpp_fadd<0x111>(v); v = dpp_fadd<0x112>(v);
  v = dpp_fadd<0x114>(v); v = dpp_fadd<0x118>(v);
  v = dpp_fadd<0x142>(v); v = dpp_fadd<0x143>(v);
  return __int_as_float(__builtin_amdgcn_readlane(__float_as_int(v), 63));
}

// ---------------- kNN v18: v14 + strength-reduced c-loop (running pointers instead of
// per-c 64-bit address muls; same FMA order -> bit-exact), simplified argmax ----------
template<int C, int M>
__global__ __launch_bounds__(256, 4) void knn_kernel(const float* __restrict__ X,
                                                     const float* __restrict__ sq,
                                                     int* __restrict__ idxout){
  const int b = blockIdx.y;
  const int n0 = blockIdx.x * M;
  const int t = threadIdx.x;
  __shared__ __align__(16) float dist[4][NPTS];   // the ONLY LDS: 32 KB
  const float* xb = X + (size_t)b*C*NPTS;

  const int m0 = t * 8;
  f32x2 acc2[M][4];
  #pragma unroll
  for (int i=0;i<M;++i)
    #pragma unroll
    for (int j=0;j<4;++j) acc2[i][j] = (f32x2){0.f, 0.f};
  {
    const float* pm = xb + m0;        // lane candidate stream (stride NPTS per c)
    const float* pu = xb + n0;        // wave-uniform center stream
    #pragma unroll 2
    for (int c=0;c<C;++c){
      const float4 xa = *(const float4*)pm;
      const float4 xc = *(const float4*)(pm + 4);
      const f32x2 xm2[4] = {(f32x2){xa.x,xa.y}, (f32x2){xa.z,xa.w},
                            (f32x2){xc.x,xc.y}, (f32x2){xc.z,xc.w}};
      #pragma unroll
      for (int i4=0; i4<M/4; ++i4){
        const float4 cq = *(const float4*)(pu + i4*4);   // uniform 16B broadcast
        const float cvr[4] = {cq.x, cq.y, cq.z, cq.w};
        #pragma unroll
        for (int r=0;r<4;++r){
          const f32x2 cv2 = (f32x2){cvr[r], cvr[r]};
          #pragma unroll
          for (int j=0;j<4;++j) acc2[i4*4+r][j] += cv2*xm2[j];   // v_pk_fma_f32
        }
      }
      pm += NPTS; pu += NPTS;
    }
  }
  {
    const float4 sa = *(const float4*)&sq[b*NPTS + m0];
    const float4 sb = *(const float4*)&sq[b*NPTS + m0 + 4];
    const f32x2 sm2[4] = {(f32x2){sa.x,sa.y}, (f32x2){sa.z,sa.w},
                          (f32x2){sb.x,sb.y}, (f32x2){sb.z,sb.w}};
    #pragma unroll
    for (int i4=0; i4<M/4; ++i4){
      const float4 sqc = *(const float4*)&sq[b*NPTS + n0 + i4*4];   // uniform
      const float sir[4] = {sqc.x, sqc.y, sqc.z, sqc.w};
      #pragma unroll
      for (int r=0;r<4;++r){
        const f32x2 si2 = (f32x2){sir[r], sir[r]};
        #pragma unroll
        for (int j=0;j<4;++j)
          acc2[i4*4+r][j] = (f32x2){2.f,2.f}*acc2[i4*4+r][j] - si2 - sm2[j];
      }
    }
  }

  const int wv = t >> 6, lane = t & 63;
  const int su0 = (((2*t)   ) ^ ((t>>2)&7)) * 4;
  const int su1 = (((2*t)+1 ) ^ ((t>>2)&7)) * 4;
  #pragma unroll
  for (int rep=0; rep<M/4; ++rep){
    #pragma unroll
    for (int i=0;i<4;++i){
      const int r = rep*4 + i;
      *(float4*)&dist[i][su0] = make_float4(acc2[r][0].x, acc2[r][0].y, acc2[r][1].x, acc2[r][1].y);
      *(float4*)&dist[i][su1] = make_float4(acc2[r][2].x, acc2[r][2].y, acc2[r][3].x, acc2[r][3].y);
    }
    __syncthreads();
    float s0=NEG_INF,s1=NEG_INF,s2=NEG_INF,s3=NEG_INF;
    int   i0=0x7fffffff,i1=0x7fffffff,i2=0x7fffffff,i3=0x7fffffff;
    #pragma unroll
    for (int jb=0;jb<8;++jb){
      const int u = lane*8 + jb;
      const float4 q = *(const float4*)&dist[wv][(u ^ (lane&7))*4];
      const float qe[4] = {q.x, q.y, q.z, q.w};
      #pragma unroll
      for (int e=0;e<4;++e){
        const float v = qe[e];
        const int   m = lane*32 + jb*4 + e;
        const bool b0 = v > s0, b1 = v > s1, b2 = v > s2, b3 = v > s3;
        const float n0_ = b0 ? v : s0;            const int q0 = b0 ? m : i0;
        const float n1_ = b0 ? s0 : (b1 ? v : s1); const int q1 = b0 ? i0 : (b1 ? m : i1);
        const float n2_ = b1 ? s1 : (b2 ? v : s2); const int q2 = b1 ? i1 : (b2 ? m : i2);
        const float n3_ = b2 ? s2 : (b3 ? v : s3); const int q3 = b2 ? i2 : (b3 ? m : i3);
        s0=n0_;s1=n1_;s2=n2_;s3=n3_; i0=q0;i1=q1;i2=q2;i3=q3;
      }
    }
    int rem = 4;
    int* row = idxout + ((size_t)b*NPTS + n0 + rep*4 + wv)*KNN;
    for (int sel=0; sel<KNN; ++sel){
      const int widx = wave_argmax_idx(s0, i0);
      if (lane == 0) row[sel] = widx;
      if ((widx >> 5) == lane){
        const float lastv = s0; const int lasti = i0;
        s0=s1;i0=i1; s1=s2;i1=i2; s2=s3;i2=i3;
        rem--;
        if (rem == 0){
          float nv = NEG_INF; int ni = 0x7fffffff;
          #pragma unroll 2
          for (int jb=0;jb<8;++jb){
            const int u = lane*8 + jb;
            const float4 q = *(const float4*)&dist[wv][(u ^ (lane&7))*4];
            const float qe[4] = {q.x, q.y, q.z, q.w};
            #pragma unroll
            for (int e=0;e<4;++e){
              const float vv = qe[e];
              const int   mi = lane*32 + jb*4 + e;
              const bool ok = (vv < lastv) || (vv == lastv && mi > lasti);
              if (ok && vv > nv){ nv = vv; ni = mi; }
            }
          }
          s0 = nv; i0 = ni; rem = 1;
        }
      }
    }
    __syncthreads();
  }
}

// ---------------- prep_all v2: xt0sq (critical path, FIRST) + all weight preps + zero --
__global__ __launch_bounds__(256) void prep_all_kernel(
    const float* __restrict__ x,
    const float* __restrict__ w1, const float* __restrict__ w2,
    const float* __restrict__ w3, const float* __restrict__ w4,
    const float* __restrict__ w5,
    float* __restrict__ xT0, float* __restrict__ sqx,
    float* __restrict__ wnT1, float* __restrict__ wdT1,
    unsigned short* __restrict__ wn2, unsigned short* __restrict__ wd2,
    unsigned short* __restrict__ wn3, unsigned short* __restrict__ wd3,
    unsigned short* __restrict__ wn4, unsigned short* __restrict__ wd4,
    unsigned short* __restrict__ w5hi, unsigned short* __restrict__ w5lo,
    float* __restrict__ out5){
  int i = blockIdx.x*256 + threadIdx.x;
  if (i < BATCH*NPTS){                  // xt0 + layer-1 sqnorm (needed first by knn<3>)
    int b = i / NPTS, n = i - b*NPTS;
    const float* xb = x + (size_t)b*3*NPTS;
    float v0 = xb[n], v1 = xb[NPTS + n], v2 = xb[2*NPTS + n];
    float* o = xT0 + ((size_t)i)*3;
    o[0]=v0; o[1]=v1; o[2]=v2;
    float s = 0.f;
    s += v0*v0; s += v1*v1; s += v2*v2;
    sqx[i] = s;
    return;
  }
  i -= BATCH*NPTS;
  if (i < 131072){                      // w5 split-bf16
    float4 v = *(const float4*)&w5[(size_t)i*4];
    unsigned short h0=bf16r(v.x), h1=bf16r(v.y), h2=bf16r(v.z), h3=bf16r(v.w);
    unsigned short l0=bf16r(v.x-bf2f(h0)), l1=bf16r(v.y-bf2f(h1)),
                   l2=bf16r(v.z-bf2f(h2)), l3=bf16r(v.w-bf2f(h3));
    *(uint2*)&w5hi[(size_t)i*4] = make_uint2((unsigned)h0|((unsigned)h1<<16), (unsigned)h2|((unsigned)h3<<16));
    *(uint2*)&w5lo[(size_t)i*4] = make_uint2((unsigned)l0|((unsigned)l1<<16), (unsigned)l2|((unsigned)l3<<16));
    return;
  }
  i -= 131072;
  if (i < 8192){ out5[i] = 0.f; return; }   // zero out5
  i -= 8192;
  if (i < 192){                         // layer-1 fp32 prep
    int c = i >> 6, o = i & 63;
    float a = w1[(size_t)o*6 + c];
    wnT1[c*64 + o] = a;
    wdT1[c*64 + o] = w1[(size_t)o*6 + 3 + c] - a;
    return;
  }
  i -= 192;
  if (i < 4096){                        // w2: O=64 C=64
    int c = i & 63, o = i >> 6;
    float a = w2[(size_t)o*128 + c];
    float d = w2[(size_t)o*128 + 64 + c] - a;
    wn2[i] = bf16r(a); wd2[i] = bf16r(d);
    return;
  }
  i -= 4096;
  if (i < 8192){                        // w3: O=128 C=64
    int c = i & 63, o = i >> 6;
    float a = w3[(size_t)o*128 + c];
    float d = w3[(size_t)o*128 + 64 + c] - a;
    wn3[i] = bf16r(a); wd3[i] = bf16r(d);
    return;
  }
  i -= 8192;
  if (i < 32768){                       // w4: O=256 C=128
    int c = i & 127, o = i >> 7;
    float a = w4[(size_t)o*256 + c];
    float d = w4[(size_t)o*256 + 128 + c] - a;
    wn4[i] = bf16r(a); wd4[i] = bf16r(d);
    return;
  }
}

// ---------------- generic tiled transpose: in[R][Cc] -> out[Cc][R], per z-slice ----------------
__global__ __launch_bounds__(256) void transpose2d_kernel(const float* __restrict__ in,
    float* __restrict__ out, int R, int Cc){
  __shared__ float tile[32][33];
  const size_t boff = (size_t)blockIdx.z * (size_t)R * Cc;
  const int c0 = blockIdx.x*32, r0 = blockIdx.y*32;
  const int tx = threadIdx.x & 31, ty = threadIdx.x >> 5;
  #pragma unroll
  for (int j=0;j<4;++j){
    int r = ty*4 + j;
    tile[r][tx] = in[boff + (size_t)(r0+r)*Cc + c0 + tx];
  }
  __syncthreads();
  #pragma unroll
  for (int j=0;j<4;++j){
    int r = ty*4 + j;
    out[boff + (size_t)(c0+r)*R + r0 + tx] = tile[tx][r];
  }
}

// ---------------- edge conv layer 1 (C=3, fp32) + fused sqnorm + xcat split write ------
__global__ __launch_bounds__(256) void edgeconv1_kernel(const float* __restrict__ xT0,
    const int* __restrict__ idx, const float* __restrict__ wnT, const float* __restrict__ wdT,
    const float* __restrict__ g, const float* __restrict__ bb, float* __restrict__ outT,
    float* __restrict__ sqout, unsigned short* __restrict__ xhi,
    unsigned short* __restrict__ xlo){
  const int b = blockIdx.y, n0 = blockIdx.x*4, t = threadIdx.x;
  __shared__ float nbr[4][KNN][3];
  __shared__ float ctr[4][3];
  __shared__ int   idxs[4][KNN];
  __shared__ float sqv[4][64];
  const float* xb = xT0 + (size_t)b*NPTS*3;
  if (t < 4*KNN) idxs[t/KNN][t%KNN] = idx[((size_t)b*NPTS + n0 + t/KNN)*KNN + (t%KNN)];
  if (t >= 128 && t < 140){ int i = t-128; ctr[i/3][i%3] = xb[(size_t)(n0 + i/3)*3 + i%3]; }
  __syncthreads();
  for (int i=t; i<4*KNN*3; i+=256){
    int p = i/(KNN*3), r = i - p*(KNN*3), k = r/3, c = r - k*3;
    nbr[p][k][c] = xb[(size_t)idxs[p][k]*3 + c];
  }
  __syncthreads();
  const int p = t >> 6, o = t & 63;
  const float wn0 = wnT[o], wn1 = wnT[64+o], wn2 = wnT[128+o];
  const float cst = ctr[p][0]*wdT[o] + ctr[p][1]*wdT[64+o] + ctr[p][2]*wdT[128+o];
  float best = NEG_INF;
  #pragma unroll
  for (int k=0;k<KNN;++k){
    float a = nbr[p][k][0]*wn0 + nbr[p][k][1]*wn1 + nbr[p][k][2]*wn2;
    best = fmaxf(best, a);
  }
  float vv = (best + cst) * bn_scale(g[o]) + bb[o];
  vv = fmaxf(vv, 0.f);
  const size_t bn_ = (size_t)b*NPTS + n0 + p;
  outT[bn_*64 + o] = vv;
  { unsigned short h = bf16r(vv);
    xhi[bn_*512 + o] = h;
    xlo[bn_*512 + o] = bf16r(vv - bf2f(h)); }
  sqv[p][o] = vv;
  __syncthreads();
  if (t < 4){                           // exact ascending-o sum == sqnorm order
    float s = 0.f;
    for (int oo=0; oo<64; ++oo){ float q = sqv[t][oo]; s += q*q; }
    sqout[(size_t)b*NPTS + n0 + t] = s;
  }
}

// ---------------- edge conv MFMA (bf16): block = 4 points --------------------------------
// SQ: fused sqnorm for next layer's knn; XOFF: xcat slice offset; WF: write float outT
template<int C, int O, bool SQ, int XOFF, bool WF>
__global__ __launch_bounds__(256) void edgeconv_mfma(const float* __restrict__ xT,
    const int* __restrict__ idx,
    const unsigned short* __restrict__ wn_bf, const unsigned short* __restrict__ wd_bf,
    const float* __restrict__ g, const float* __restrict__ bb, float* __restrict__ outT,
    float* __restrict__ sqout, unsigned short* __restrict__ xhi,
    unsigned short* __restrict__ xlo){
  constexpr int ROWS = 112;
  constexpr int CP   = C + 8;
  constexpr int KS   = C / 32;
  constexpr int NTW  = O / 64;
  __shared__ __align__(16) unsigned short A[ROWS][CP];
  __shared__ unsigned int res[4][O];
  __shared__ float cst_s[4][O];
  __shared__ int idxs[4][KNN];
  __shared__ float sqv[4][SQ ? O : 4];
  const int b = blockIdx.y, n0 = blockIdx.x*4, t = threadIdx.x;
  const float* xTb = xT + (size_t)b*NPTS*C;
  if (t < 4*KNN) idxs[t/KNN][t%KNN] = idx[((size_t)b*NPTS + n0 + t/KNN)*KNN + (t%KNN)];
  for (int i=t; i<4*O; i+=256) res[i/O][i & (O-1)] = 0u;
  __syncthreads();
  for (int i=t; i<ROWS*(C/4); i+=256){
    int r = i/(C/4), c4 = i - r*(C/4);
    float4 v = make_float4(0.f,0.f,0.f,0.f);
    if (r < 96){
      int p = r/24, kk = r - p*24;
      int src = idxs[p][kk < KNN ? kk : 0];
      v = *(const float4*)&xTb[(size_t)src*C + c4*4];
    } else if (r < 100){
      v = *(const float4*)&xTb[(size_t)(n0 + (r-96))*C + c4*4];
    }
    unsigned int lo = (unsigned int)bf16r(v.x) | ((unsigned int)bf16r(v.y) << 16);
    unsigned int hi = (unsigned int)bf16r(v.z) | ((unsigned int)bf16r(v.w) << 16);
    *(uint2*)&A[r][c4*4] = make_uint2(lo, hi);
  }
  __syncthreads();

  const int wv = t >> 6, l = t & 63;
  const int lane15 = l & 15, quad = l >> 4;
  bfrag Bn[NTW][KS];
  #pragma unroll
  for (int nt=0; nt<NTW; ++nt){
    const int col = (wv*NTW + nt)*16 + lane15;
    #pragma unroll
    for (int s=0; s<KS; ++s)
      Bn[nt][s] = *(const bfrag*)&wn_bf[(size_t)col*C + s*32 + quad*8];
  }
  #pragma unroll
  for (int mt=0; mt<7; ++mt){
    bfrag Af[KS];
    #pragma unroll
    for (int s=0; s<KS; ++s)
      Af[s] = *(const bfrag*)&A[mt*16 + lane15][s*32 + quad*8];
    if (mt < 6){
      const int rbase = mt*16 + quad*4;
      const int p = rbase / 24;
      #pragma unroll
      for (int nt=0; nt<NTW; ++nt){
        f32x4 acc = {0.f,0.f,0.f,0.f};
        #pragma unroll
        for (int s=0; s<KS; ++s)
          acc = __builtin_amdgcn_mfma_f32_16x16x32_bf16(Af[s], Bn[nt][s], acc, 0, 0, 0);
        float m = fmaxf(fmaxf(acc[0], acc[1]), fmaxf(acc[2], acc[3]));
        const int col = (wv*NTW + nt)*16 + lane15;
        atomicMax(&res[p][col], fenc(m));
      }
    } else {
      #pragma unroll
      for (int nt=0; nt<NTW; ++nt){
        const int col = (wv*NTW + nt)*16 + lane15;
        f32x4 acc = {0.f,0.f,0.f,0.f};
        #pragma unroll
        for (int s=0; s<KS; ++s){
          bfrag Bd = *(const bfrag*)&wd_bf[(size_t)col*C + s*32 + quad*8];
          acc = __builtin_amdgcn_mfma_f32_16x16x32_bf16(Af[s], Bd, acc, 0, 0, 0);
        }
        if (quad == 0){
          #pragma unroll
          for (int r=0;r<4;++r) cst_s[r][col] = acc[r];
        }
      }
    }
  }
  __syncthreads();
  for (int i=t; i<4*O; i+=256){
    int p = i/O, o = i - p*O;
    float mx = fdec(res[p][o]);
    float vv = (mx + cst_s[p][o]) * bn_scale(g[o]) + bb[o];
    vv = fmaxf(vv, 0.f);
    const size_t bn_ = (size_t)b*NPTS + n0 + p;
    if (WF) outT[bn_*O + o] = vv;
    { unsigned short h = bf16r(vv);          // xcat slice fused (bit-exact vs old xcat)
      xhi[bn_*512 + XOFF + o] = h;
      xlo[bn_*512 + XOFF + o] = bf16r(vv - bf2f(h)); }
    if (SQ) sqv[p][o] = vv;
  }
  if (SQ){
    __syncthreads();
    if (t < 4){
      float s = 0.f;
      for (int oo=0; oo<O; ++oo){ float q = sqv[t][oo]; s += q*q; }
      sqout[(size_t)b*NPTS + n0 + t] = s;
    }
  }
}

// ---------------- conv5 v3 (round-4 proven): LDS-staged split-bf16 MFMA GEMM + max -----
__global__ __launch_bounds__(256) void conv5_v3(const unsigned short* __restrict__ xhi,
    const unsigned short* __restrict__ xlo, const unsigned short* __restrict__ whi,
    const unsigned short* __restrict__ wlo, const float* __restrict__ g,
    const float* __restrict__ bb, float* __restrict__ out5){
  __shared__ __align__(16) unsigned short Ah_s[128*32];
  __shared__ __align__(16) unsigned short Al_s[128*32];
  __shared__ __align__(16) unsigned short Bh_s[64*32];
  __shared__ __align__(16) unsigned short Bl_s[64*32];
  const int t = threadIdx.x;
  const int row0 = blockIdx.x*128, o0 = blockIdx.y*64;
  const int b = row0 / NPTS;   // 128 | NPTS, so a block never straddles batches
  const int wv = t >> 6, l = t & 63, lane15 = l & 15, quad = l >> 4;
  const int ar = t >> 2, ac = (t & 3)*8;
  const unsigned short* gAh0 = xhi + (size_t)(row0 + ar)*512 + ac;
  const unsigned short* gAh1 = xhi + (size_t)(row0 + 64 + ar)*512 + ac;
  const unsigned short* gAl0 = xlo + (size_t)(row0 + ar)*512 + ac;
  const unsigned short* gAl1 = xlo + (size_t)(row0 + 64 + ar)*512 + ac;
  const unsigned short* gBh  = whi + (size_t)(o0 + ar)*512 + ac;
  const unsigned short* gBl  = wlo + (size_t)(o0 + ar)*512 + ac;

  uint4 pf0 = *(const uint4*)gAh0;
  uint4 pf1 = *(const uint4*)gAh1;
  uint4 pf2 = *(const uint4*)gAl0;
  uint4 pf3 = *(const uint4*)gAl1;
  uint4 pf4 = *(const uint4*)gBh;
  uint4 pf5 = *(const uint4*)gBl;

  f32x4 acc[2][4];
  #pragma unroll
  for (int mt=0;mt<2;++mt)
    #pragma unroll
    for (int nt=0;nt<4;++nt) acc[mt][nt] = (f32x4){0.f,0.f,0.f,0.f};

  for (int ks=0; ks<16; ++ks){
    *(uint4*)&Ah_s[t*8]        = pf0;
    *(uint4*)&Ah_s[2048 + t*8] = pf1;
    *(uint4*)&Al_s[t*8]        = pf2;
    *(uint4*)&Al_s[2048 + t*8] = pf3;
    *(uint4*)&Bh_s[t*8]        = pf4;
    *(uint4*)&Bl_s[t*8]        = pf5;
    __syncthreads();
    if (ks < 15){
      const int koff = (ks+1)*32;
      pf0 = *(const uint4*)(gAh0 + koff);
      pf1 = *(const uint4*)(gAh1 + koff);
      pf2 = *(const uint4*)(gAl0 + koff);
      pf3 = *(const uint4*)(gAl1 + koff);
      pf4 = *(const uint4*)(gBh  + koff);
      pf5 = *(const uint4*)(gBl  + koff);
    }
    bfrag Afh[2], Afl[2], Bfh[4], Bfl[4];
    #pragma unroll
    for (int mt=0;mt<2;++mt){
      const int m = wv*32 + mt*16 + lane15;
      Afh[mt] = *(const bfrag*)&Ah_s[m*32 + quad*8];
      Afl[mt] = *(const bfrag*)&Al_s[m*32 + quad*8];
    }
    #pragma unroll
    for (int nt=0;nt<4;++nt){
      const int oc = nt*16 + lane15;
      Bfh[nt] = *(const bfrag*)&Bh_s[oc*32 + quad*8];
      Bfl[nt] = *(const bfrag*)&Bl_s[oc*32 + quad*8];
    }
    #pragma unroll
    for (int mt=0;mt<2;++mt)
      #pragma unroll
      for (int nt=0;nt<4;++nt){
        acc[mt][nt] = __builtin_amdgcn_mfma_f32_16x16x32_bf16(Afh[mt], Bfh[nt], acc[mt][nt], 0, 0, 0);
        acc[mt][nt] = __builtin_amdgcn_mfma_f32_16x16x32_bf16(Afl[mt], Bfh[nt], acc[mt][nt], 0, 0, 0);
        acc[mt][nt] = __builtin_amdgcn_mfma_f32_16x16x32_bf16(Afh[mt], Bfl[nt], acc[mt][nt], 0, 0, 0);
      }
    __syncthreads();
  }
  #pragma unroll
  for (int nt=0;nt<4;++nt){
    float m = NEG_INF;
    #pragma unroll
    for (int mt=0;mt<2;++mt)
      #pragma unroll
      for (int r=0;r<4;++r) m = fmaxf(m, acc[mt][nt][r]);
    m = fmaxf(m, __shfl_xor(m, 16, 64));
    m = fmaxf(m, __shfl_xor(m, 32, 64));
    if (quad == 0){
      const int o = o0 + nt*16 + lane15;
      float vv = fmaxf(m * bn_scale(g[o]) + bb[o], 0.f);
      atomicMax((int*)&out5[(size_t)b*1024 + o], __float_as_int(vv));
    }
  }
}

// ---------------- FC layers: one wave per (b,o), coalesced lane-strided reads ----------
__global__ __launch_bounds__(256) void fc_wave_kernel(const float* __restrict__ in,
    const float* __restrict__ w, const float* __restrict__ g, const float* __restrict__ bb,
    float* __restrict__ out, int IN, int O){
  const int wid = (blockIdx.x*256 + threadIdx.x) >> 6;
  const int lane = threadIdx.x & 63;
  if (wid >= BATCH*O) return;
  const int b = wid / O, o = wid - b*O;
  const float* inb = in + (size_t)b*IN;
  const float* wo  = w + (size_t)o*IN;
  float s = 0.f;
  for (int c = lane; c < IN; c += 64) s += inb[c]*wo[c];
  s = wave_sum(s);
  if (lane == 0){
    if (g){ s = s*bn_scale(g[o]) + bb[o]; s = fmaxf(s, 0.f); }
    out[wid] = s;
  }
}

extern "C" void kernel_launch(void* const* d_in, const int* in_sizes, int n_in,
                              void* d_out, int out_size, void* d_ws, size_t ws_size,
                              hipStream_t stream){
  const float* x   = (const float*)d_in[0];
  const float* w1  = (const float*)d_in[1];
  const float* w2  = (const float*)d_in[2];
  const float* w3  = (const float*)d_in[3];
  const float* w4  = (const float*)d_in[4];
  const float* w5  = (const float*)d_in[5];
  const float* fw1 = (const float*)d_in[6];
  const float* fw2 = (const float*)d_in[7];
  const float* fw3 = (const float*)d_in[8];
  const float* g1 = (const float*)d_in[9];  const float* b1 = (const float*)d_in[10];
  const float* g2 = (const float*)d_in[11]; const float* b2 = (const float*)d_in[12];
  const float* g3 = (const float*)d_in[13]; const float* b3 = (const float*)d_in[14];
  const float* g4 = (const float*)d_in[15]; const float* b4 = (const float*)d_in[16];
  const float* g5 = (const float*)d_in[17]; const float* b5 = (const float*)d_in[18];
  const float* g6 = (const float*)d_in[19]; const float* b6 = (const float*)d_in[20];
  const float* g7 = (const float*)d_in[21]; const float* b7 = (const float*)d_in[22];

  float* ws = (float*)d_ws;
  size_t off = 0;
  // x1..x3 channel-major (knn inputs)
  float* x1  = ws + off; off += (size_t)BATCH*64*NPTS;
  float* x2  = ws + off; off += (size_t)BATCH*64*NPTS;
  float* x3  = ws + off; off += (size_t)BATCH*128*NPTS;
  unsigned short* xcat_hi = (unsigned short*)(ws + off); off += (size_t)BATCH*256*NPTS;
  float* x1T = ws + off; off += (size_t)BATCH*64*NPTS;
  float* x2T = ws + off; off += (size_t)BATCH*64*NPTS;
  float* x3T = ws + off; off += (size_t)BATCH*128*NPTS;
  // old x4T slot hosts xcat_lo (layer-4 writes its xcat slice directly)
  unsigned short* xcat_lo = (unsigned short*)(ws + off); off += (size_t)BATCH*256*NPTS;
  float* xT0 = ws + off; off += (size_t)BATCH*3*NPTS;
  float* sq  = ws + off; off += (size_t)BATCH*NPTS;
  int*  idx  = (int*)(ws + off); off += (size_t)BATCH*NPTS*KNN;
  float* out5 = ws + off; off += BATCH*1024;
  float* h6 = ws + off;   off += BATCH*512;
  float* h7 = ws + off;   off += BATCH*256;
  float* wnT1 = ws + off; off += 3*64;
  float* wdT1 = ws + off; off += 3*64;
  unsigned short* wn2 = (unsigned short*)(ws + off); off += 64*64/2;
  unsigned short* wd2 = (unsigned short*)(ws + off); off += 64*64/2;
  unsigned short* wn3 = (unsigned short*)(ws + off); off += 128*64/2;
  unsigned short* wd3 = (unsigned short*)(ws + off); off += 128*64/2;
  unsigned short* wn4 = (unsigned short*)(ws + off); off += 256*128/2;
  unsigned short* wd4 = (unsigned short*)(ws + off); off += 256*128/2;
  unsigned short* w5hi = (unsigned short*)(ws + off); off += 1024*512/2;
  unsigned short* w5lo = (unsigned short*)(ws + off); off += 1024*512/2;

  dim3 gridKNN8(NPTS/8, BATCH);
  dim3 gridEC(NPTS/4, BATCH);

  // xt0+sq (critical path, first blocks) + all weight preps + out5 zero, one launch
  prep_all_kernel<<<785, 256, 0, stream>>>(x, w1, w2, w3, w4, w5, xT0, sq, wnT1, wdT1,
                                           wn2, wd2, wn3, wd3, wn4, wd4,
                                           w5hi, w5lo, out5);
  // layer 1 (C=3 -> 64, fp32)
  knn_kernel<3,8><<<gridKNN8, 256, 0, stream>>>(x, sq, idx);
  edgeconv1_kernel<<<gridEC, 256, 0, stream>>>(xT0, idx, wnT1, wdT1, g1, b1, x1T, sq,
                                               xcat_hi, xcat_lo);
  transpose2d_kernel<<<dim3(2,64,BATCH), 256, 0, stream>>>(x1T, x1, NPTS, 64);
  // layer 2 (C=64 -> 64, bf16 MFMA); writes sq(x2) + xcat slice [64:128)
  knn_kernel<64,8><<<gridKNN8, 256, 0, stream>>>(x1, sq, idx);
  edgeconv_mfma<64,64,true,64,true><<<gridEC, 256, 0, stream>>>(x1T, idx, wn2, wd2, g2, b2,
                                                                x2T, sq, xcat_hi, xcat_lo);
  transpose2d_kernel<<<dim3(2,64,BATCH), 256, 0, stream>>>(x2T, x2, NPTS, 64);
  // layer 3 (C=64 -> 128, bf16 MFMA); writes sq(x3) + xcat slice [128:256)
  knn_kernel<64,8><<<gridKNN8, 256, 0, stream>>>(x2, sq, idx);
  edgeconv_mfma<64,128,true,128,true><<<gridEC, 256, 0, stream>>>(x2T, idx, wn3, wd3, g3, b3,
                                                                  x3T, sq, xcat_hi, xcat_lo);
  transpose2d_kernel<<<dim3(4,64,BATCH), 256, 0, stream>>>(x3T, x3, NPTS, 128);
  // layer 4 (C=128 -> 256, bf16 MFMA); writes ONLY xcat slice [256:512)
  knn_kernel<128,8><<<gridKNN8, 256, 0, stream>>>(x3, sq, idx);
  edgeconv_mfma<128,256,false,256,false><<<gridEC, 256, 0, stream>>>(x3T, idx, wn4, wd4, g4, b4,
                                                                     nullptr, nullptr,
                                                                     xcat_hi, xcat_lo);
  // conv5 (split-bf16 MFMA, LDS-staged) + global max over n
  conv5_v3<<<dim3(BATCH*NPTS/128, 16), 256, 0, stream>>>(xcat_hi, xcat_lo, w5hi, w5lo, g5, b5, out5);
  // FC head (wave-per-output, coalesced)
  fc_wave_kernel<<<(BATCH*512*64)/256, 256, 0, stream>>>(out5, fw1, g6, b6, h6, 1024, 512);
  fc_wave_kernel<<<(BATCH*256*64)/256, 256, 0, stream>>>(h6, fw2, g7, b7, h7, 512, 256);
  fc_wave_kernel<<<(BATCH*40*64 + 255)/256, 256, 0, stream>>>(h7, fw3, nullptr, nullptr, (float*)d_out, 256, 40);
}